// Round 2
// baseline (299.217 us; speedup 1.0000x reference)
//
#include <hip/hip_runtime.h>
#include <hip/hip_bf16.h>
#include <math.h>
#include <stdint.h>

#define N_NODES 50000
#define N_PAD   50048   // padded rows for MFMA tile overrun (row 50000 = zero/dummy row)
#define N_EDGES 800000
#define N_GRAPHS 256
#define F_IN 64
#define F_HID 128
#define N_HID 512
#define N_OUT 256

#define NBKT   196           // buckets of 256 nodes (dst >> 8)
#define BKT_S  6144          // per-bucket binned capacity (expected 4082, +32 sigma)
#define BKT_CAP 8192         // fixed per-bucket CSR capacity (expected 5900, +18 sigma)
#define EPB    3328          // edges per bin_edges block (13 * 256)
#define NBIN_BLK ((N_EDGES + EPB - 1) / EPB)   // 241
#define DUMMY_NODE N_NODES   // zero row index for CSR pad slots

using bf16x8 = __attribute__((ext_vector_type(8))) short;   // MFMA A/B frag (4 VGPRs)
using f32x4  = __attribute__((ext_vector_type(4))) float;   // MFMA C/D frag

// pack two fp32 into a uint holding two bf16 (RNE); low16 = a, high16 = b
__device__ __forceinline__ unsigned int bf16pair(float a, float b) {
    unsigned int ua = __float_as_uint(a);
    unsigned int ub = __float_as_uint(b);
    ua += 0x7fffu + ((ua >> 16) & 1u);
    ub += 0x7fffu + ((ub >> 16) & 1u);
    return (ua >> 16) | (ub & 0xffff0000u);
}
__device__ __forceinline__ unsigned short bf16one(float a) {
    unsigned int ua = __float_as_uint(a);
    ua += 0x7fffu + ((ua >> 16) & 1u);
    return (unsigned short)(ua >> 16);
}
__device__ __forceinline__ float bf16lo(unsigned int u) { return __uint_as_float(u << 16); }
__device__ __forceinline__ float bf16hi(unsigned int u) { return __uint_as_float(u & 0xffff0000u); }

// accumulate 8 bf16 features from a uint4 into a[0..7]
__device__ __forceinline__ void acc8(float* a, uint4 r) {
    a[0] += bf16lo(r.x);  a[1] += bf16hi(r.x);
    a[2] += bf16lo(r.y);  a[3] += bf16hi(r.y);
    a[4] += bf16lo(r.z);  a[5] += bf16hi(r.z);
    a[6] += bf16lo(r.w);  a[7] += bf16hi(r.w);
}

// ---------------------------------------------------------------------------
// K0 (merged): xb'[s] = bf16(dis[s] * x[s]) + zero pad row; both weight tables
// fp32 [K][128] -> bf16 [128][K] in the same dispatch.
__global__ void cvt_all(const float* __restrict__ in, const float* __restrict__ dis,
                        unsigned int* __restrict__ xb,
                        const float* __restrict__ W0, unsigned short* __restrict__ W0Tb,
                        const float* __restrict__ W1, unsigned short* __restrict__ W1Tb) {
    const int NX = N_NODES * F_IN / 4;          // 800000 float4 slots
    int idx = blockIdx.x * blockDim.x + threadIdx.x;
    if (idx < NX) {
        int node = idx >> 4;                    // 16 float4 per 64-f row
        float d = dis[node];
        float4 v = ((const float4*)in)[idx];
        ((uint2*)xb)[idx] = make_uint2(bf16pair(d * v.x, d * v.y),
                                       bf16pair(d * v.z, d * v.w));
        if (idx < 16)                            // zero dummy row 50000
            ((uint2*)xb)[(size_t)N_NODES * 16 + idx] = make_uint2(0u, 0u);
    } else {
        int j = idx - NX;
        const int N0 = F_IN * 128;
        const int N1 = F_HID * 128;
        if (j < N0) {
            int k = j >> 7, n = j & 127;
            W0Tb[n * F_IN + k] = bf16one(W0[j]);
        } else if (j < N0 + N1) {
            int jj = j - N0;
            int k = jj >> 7, n = jj & 127;
            W1Tb[n * F_HID + k] = bf16one(W1[jj]);
        }
    }
}

// ---------------------------------------------------------------------------
// K1: bin edges by dst>>8 through LDS staging (privatized binning).
__global__ __launch_bounds__(256) void bin_edges(const int* __restrict__ ei,
                                                 int* __restrict__ bucketCur,
                                                 unsigned int* __restrict__ binned) {
    __shared__ int hist[NBKT];
    __shared__ int lbase[NBKT];
    __shared__ int lcur[NBKT];
    __shared__ int gbase[NBKT];
    __shared__ int scn[256];
    __shared__ unsigned int staging[EPB];
    int tid = threadIdx.x;
    int base = blockIdx.x * EPB;
    int cnt = N_EDGES - base; if (cnt > EPB) cnt = EPB;
    if (tid < NBKT) hist[tid] = 0;
    __syncthreads();
    unsigned int pk[13]; int nk = 0;
#pragma unroll
    for (int u = 0; u < 13; ++u) {
        int e = base + u * 256 + tid;
        if (u * 256 + tid < cnt) {
            unsigned int s = (unsigned int)ei[e];
            unsigned int d = (unsigned int)ei[N_EDGES + e];
            unsigned int b = d >> 8;
            pk[nk++] = (b << 24) | (s << 8) | (d & 255u);
        }
    }
    for (int u = 0; u < nk; ++u) atomicAdd(&hist[pk[u] >> 24], 1);
    __syncthreads();
    // parallel exclusive scan over the 196 bucket counts
    int h = (tid < NBKT) ? hist[tid] : 0;
    scn[tid] = h;
    __syncthreads();
    for (int off = 1; off < 256; off <<= 1) {
        int t = (tid >= off) ? scn[tid - off] : 0;
        __syncthreads();
        scn[tid] += t;
        __syncthreads();
    }
    if (tid < NBKT) { int e0 = scn[tid] - h; lbase[tid] = e0; lcur[tid] = e0; }
    __syncthreads();
    for (int u = 0; u < nk; ++u) {
        int pos = atomicAdd(&lcur[pk[u] >> 24], 1);
        staging[pos] = pk[u];
    }
    if (tid < NBKT && hist[tid] > 0)
        gbase[tid] = atomicAdd(&bucketCur[tid], hist[tid]);
    __syncthreads();
    for (int k = tid; k < cnt; k += 256) {
        unsigned int v = staging[k];
        int b = v >> 24;
        binned[(size_t)b * BKT_S + gbase[b] + (k - lbase[b])] = v & 0xffffffu;
    }
}

// K2 (merged deg + scatter): histogram -> degs/dis/offsets (csrBase fixed at
// b*BKT_CAP: no inter-bucket scan), CSR built in LDS, streamed out coalesced.
__global__ __launch_bounds__(256) void deg_scatter(const unsigned int* __restrict__ binned,
                                                   const int* __restrict__ bucketCur,
                                                   int* __restrict__ degs,
                                                   float* __restrict__ dis,
                                                   int* __restrict__ offsets,
                                                   unsigned short* __restrict__ csr) {
    __shared__ int hist[256];
    __shared__ int tsum[256];
    __shared__ int lcur[256];
    __shared__ uint4 scsr4[BKT_CAP / 8];   // 16 KB CSR staging
    unsigned short* scsr = (unsigned short*)scsr4;
    int b = blockIdx.x;
    int tid = threadIdx.x;
    int node0 = b << 8;
    hist[tid] = 0;
    __syncthreads();
    int cnt = bucketCur[b];
    const unsigned int* bb = &binned[(size_t)b * BKT_S];
    for (int k = tid; k < cnt; k += 256)
        atomicAdd(&hist[bb[k] & 255u], 1);
    __syncthreads();
    int d = hist[tid];
    int s = (d + 15) & ~15;          // align-16 so aggregates run full 16-edge chunks
    tsum[tid] = s;
    __syncthreads();
    for (int off = 1; off < 256; off <<= 1) {
        int t = (tid >= off) ? tsum[tid - off] : 0;
        __syncthreads();
        tsum[tid] += t;
        __syncthreads();
    }
    int excl = tsum[tid] - s;
    int tot = tsum[255];              // multiple of 16
    int csrB = b * BKT_CAP;
    int node = node0 + tid;
    if (node < N_NODES) {
        degs[node] = d;
        dis[node] = rsqrtf((float)(d + 1));
        offsets[node] = csrB + excl;
    }
    lcur[tid] = excl;
    // dummy-fill the aligned LDS region (uint2 = 4 entries; tot % 16 == 0)
    uint2 dv = make_uint2(0xC350C350u, 0xC350C350u);   // 50000 | 50000<<16
    for (int k = tid; k < (tot >> 2); k += 256) ((uint2*)scsr)[k] = dv;
    __syncthreads();
    for (int k = tid; k < cnt; k += 256) {
        unsigned int v = bb[k];
        int dl = v & 255u;
        int p = atomicAdd(&lcur[dl], 1);
        scsr[p] = (unsigned short)(v >> 8);
    }
    __syncthreads();
    for (int k = tid; k < (tot >> 3); k += 256)
        ((uint4*)(csr + csrB))[k] = scsr4[k];
}

// ---------------------------------------------------------------------------
// K4 (fused W0->W1): C0 = relu(axb@W0 + b0) -> bf16 -> per-wave XOR-swizzled
// LDS tile -> h_tmpb = bf16(dis * (C0@W1)). Pad rows write zeros.
__global__ __launch_bounds__(256) void gemm01_mfma(const unsigned short* __restrict__ Ab,
                                                   const unsigned short* __restrict__ W0T,
                                                   const float* __restrict__ b0,
                                                   const unsigned short* __restrict__ W1T,
                                                   const float* __restrict__ disv,
                                                   unsigned int* __restrict__ outb, int M) {
    __shared__ unsigned short tile[4][16 * 128];   // 4 KB per wave, 16 KB total
    int wv = threadIdx.x >> 6;
    int lane = threadIdx.x & 63;
    int m = lane & 15;
    int quad = lane >> 4;
    int row0 = blockIdx.x * 64 + wv * 16;
    char* tl = (char*)&tile[wv][0];
    f32x4 acc[8];
#pragma unroll
    for (int t = 0; t < 8; ++t) acc[t] = (f32x4){0.f, 0.f, 0.f, 0.f};
    // phase 1: K = 64 (axb @ W0)
#pragma unroll
    for (int ks = 0; ks < F_IN; ks += 32) {
        bf16x8 af = *(const bf16x8*)&Ab[(size_t)(row0 + m) * F_IN + ks + quad * 8];
#pragma unroll
        for (int t = 0; t < 8; ++t) {
            bf16x8 bf = *(const bf16x8*)&W0T[(size_t)(t * 16 + m) * F_IN + ks + quad * 8];
            acc[t] = __builtin_amdgcn_mfma_f32_16x16x32_bf16(af, bf, acc[t], 0, 0, 0);
        }
    }
    // epilogue 1: bias + relu -> bf16 -> swizzled LDS (row = quad*4+r, col = t*16+m)
#pragma unroll
    for (int t = 0; t < 8; ++t) {
        int col = t * 16 + m;
        float bcol = b0[col];
#pragma unroll
        for (int r = 0; r < 4; ++r) {
            int row = quad * 4 + r;
            float v = fmaxf(acc[t][r] + bcol, 0.f);
            int byte = (row * 256 + col * 2) ^ ((row & 7) << 4);
            *(unsigned short*)(tl + byte) = bf16one(v);
        }
    }
    __syncthreads();
    // phase 2: K = 128 (C0 @ W1), A-frags from swizzled LDS
#pragma unroll
    for (int t = 0; t < 8; ++t) acc[t] = (f32x4){0.f, 0.f, 0.f, 0.f};
#pragma unroll
    for (int ks = 0; ks < F_HID; ks += 32) {
        int byte = (m * 256 + ks * 2 + quad * 16) ^ ((m & 7) << 4);
        bf16x8 af = *(const bf16x8*)(tl + byte);
#pragma unroll
        for (int t = 0; t < 8; ++t) {
            bf16x8 bf = *(const bf16x8*)&W1T[(size_t)(t * 16 + m) * F_HID + ks + quad * 8];
            acc[t] = __builtin_amdgcn_mfma_f32_16x16x32_bf16(af, bf, acc[t], 0, 0, 0);
        }
    }
    // epilogue 2: dis-scale, pair-write bf16, zero pad rows
    float dr[4];
#pragma unroll
    for (int r = 0; r < 4; ++r) {
        int row = row0 + quad * 4 + r;
        dr[r] = (row < M) ? disv[row] : 0.f;
    }
#pragma unroll
    for (int t = 0; t < 8; ++t) {
        int col = t * 16 + m;
#pragma unroll
        for (int r = 0; r < 4; ++r) {
            float v = acc[t][r] * dr[r];
            float vn = __shfl_xor(v, 1, 64);    // neighbor col's value
            if ((m & 1) == 0) {
                int row = row0 + quad * 4 + r;
                outb[(size_t)row * 64 + (col >> 1)] = (row < M) ? bf16pair(v, vn) : 0u;
            }
        }
    }
}

// ---------------------------------------------------------------------------
// K5a: F=128 aggregate over PRE-SCALED bf16 table. 4 edges/inst, no tail.
template <bool RELU, bool BIAS, bool SCALEOUT>
__global__ __launch_bounds__(256) void aggregate128b(const uint4* __restrict__ hb4,
                                                     const int* __restrict__ offsets,
                                                     const int* __restrict__ degs,
                                                     const unsigned short* __restrict__ csr,
                                                     const float* __restrict__ dis,
                                                     const float* __restrict__ bias,
                                                     unsigned int* __restrict__ outb) {
    int wave = threadIdx.x >> 6;
    int lane = threadIdx.x & 63;
    int i = blockIdx.x * 4 + wave;
    int sub = lane >> 4;              // 0..3: which edge-quad
    int q   = lane & 15;              // uint4 index within the 16-uint4 row
    if (i >= N_NODES) {
        if (i == N_NODES && sub == 0)  // zero dummy row for downstream gathers
            ((uint4*)outb)[(size_t)N_NODES * 16 + q] = make_uint4(0u, 0u, 0u, 0u);
        return;
    }
    float a[8];
#pragma unroll
    for (int k = 0; k < 8; ++k) a[k] = 0.f;
    int j = offsets[i];
    int e1 = j + ((degs[i] + 15) & ~15);
    for (; j < e1; j += 16) {
        uint2 w = *(const uint2*)&csr[j + 4 * sub];
        int s0 = w.x & 0xffff, s1 = w.x >> 16;
        int s2 = w.y & 0xffff, s3 = w.y >> 16;
        uint4 r0 = hb4[(size_t)s0 * 16 + q];
        uint4 r1 = hb4[(size_t)s1 * 16 + q];
        uint4 r2 = hb4[(size_t)s2 * 16 + q];
        uint4 r3 = hb4[(size_t)s3 * 16 + q];
        acc8(a, r0); acc8(a, r1); acc8(a, r2); acc8(a, r3);
    }
#pragma unroll
    for (int k = 0; k < 8; ++k) a[k] += __shfl_xor(a[k], 16, 64);
#pragma unroll
    for (int k = 0; k < 8; ++k) a[k] += __shfl_xor(a[k], 32, 64);
    uint4 su = hb4[(size_t)i * 16 + q];     // self: weight 1 in scaled domain
    acc8(a, su);
    float dii = dis[i];
#pragma unroll
    for (int k = 0; k < 8; ++k) a[k] *= dii;
    if (BIAS) {
        float4 b0 = ((const float4*)bias)[2 * q];
        float4 b1 = ((const float4*)bias)[2 * q + 1];
        a[0] += b0.x; a[1] += b0.y; a[2] += b0.z; a[3] += b0.w;
        a[4] += b1.x; a[5] += b1.y; a[6] += b1.z; a[7] += b1.w;
    }
    if (RELU) {
#pragma unroll
        for (int k = 0; k < 8; ++k) a[k] = fmaxf(a[k], 0.f);
    }
    if (sub == 0) {
        float sc = SCALEOUT ? dii : 1.f;
        ((uint4*)outb)[(size_t)i * 16 + q] =
            make_uint4(bf16pair(sc * a[0], sc * a[1]), bf16pair(sc * a[2], sc * a[3]),
                       bf16pair(sc * a[4], sc * a[5]), bf16pair(sc * a[6], sc * a[7]));
    }
}

// K5b: F=64 aggregate over pre-scaled bf16 x-table. 8 edges/inst, no tail.
__global__ __launch_bounds__(256) void aggregate_xb(const uint4* __restrict__ xb4,
                                                    const float* __restrict__ x,
                                                    const int* __restrict__ offsets,
                                                    const int* __restrict__ degs,
                                                    const unsigned short* __restrict__ csr,
                                                    const float* __restrict__ dis,
                                                    unsigned int* __restrict__ outb) {
    int wave = threadIdx.x >> 6;
    int lane = threadIdx.x & 63;
    int i = blockIdx.x * 4 + wave;
    int sub = lane >> 3;              // 0..7: which edge-pair
    int q   = lane & 7;               // uint4 index within the 8-uint4 row
    if (i >= N_NODES) {
        if (i == N_NODES && sub == 0)
            ((uint4*)outb)[(size_t)N_NODES * 8 + q] = make_uint4(0u, 0u, 0u, 0u);
        return;
    }
    float a[8];
#pragma unroll
    for (int k = 0; k < 8; ++k) a[k] = 0.f;
    int j = offsets[i];
    int e1 = j + ((degs[i] + 15) & ~15);
    for (; j < e1; j += 16) {
        unsigned int w = *(const unsigned int*)&csr[j + 2 * sub];
        int s0 = w & 0xffff, s1 = w >> 16;
        uint4 r0 = xb4[(size_t)s0 * 8 + q];
        uint4 r1 = xb4[(size_t)s1 * 8 + q];
        acc8(a, r0); acc8(a, r1);
    }
#pragma unroll
    for (int k = 0; k < 8; ++k) a[k] += __shfl_xor(a[k], 8, 64);
#pragma unroll
    for (int k = 0; k < 8; ++k) a[k] += __shfl_xor(a[k], 16, 64);
#pragma unroll
    for (int k = 0; k < 8; ++k) a[k] += __shfl_xor(a[k], 32, 64);
    float dii = dis[i];
    float d2 = dii * dii;
    float4 sx0 = ((const float4*)x)[(size_t)i * 16 + 2 * q];       // self in fp32
    float4 sx1 = ((const float4*)x)[(size_t)i * 16 + 2 * q + 1];
    a[0] = dii * a[0] + d2 * sx0.x;  a[1] = dii * a[1] + d2 * sx0.y;
    a[2] = dii * a[2] + d2 * sx0.z;  a[3] = dii * a[3] + d2 * sx0.w;
    a[4] = dii * a[4] + d2 * sx1.x;  a[5] = dii * a[5] + d2 * sx1.y;
    a[6] = dii * a[6] + d2 * sx1.z;  a[7] = dii * a[7] + d2 * sx1.w;
    if (sub == 0)
        ((uint4*)outb)[(size_t)i * 8 + q] =
            make_uint4(bf16pair(a[0], a[1]), bf16pair(a[2], a[3]),
                       bf16pair(a[4], a[5]), bf16pair(a[6], a[7]));
}

// K5c: layer-2 aggregate FUSED with mean-pool. Wave handles 4 consecutive
// nodes (batch sorted); pooled fp32 sums flush to g_acc/g_cnt on graph change.
__global__ __launch_bounds__(256) void aggregate_pool(const uint4* __restrict__ hb4,
                                                      const int* __restrict__ offsets,
                                                      const int* __restrict__ degs,
                                                      const unsigned short* __restrict__ csr,
                                                      const float* __restrict__ dis,
                                                      const int* __restrict__ batch,
                                                      float* __restrict__ g_acc,
                                                      float* __restrict__ g_cnt) {
    const int NPW = 4;                // nodes per wave
    int wave = threadIdx.x >> 6;
    int lane = threadIdx.x & 63;
    int sub = lane >> 4;
    int q   = lane & 15;
    int i0 = (blockIdx.x * 4 + wave) * NPW;
    if (i0 >= N_NODES) return;
    float pa[8];
#pragma unroll
    for (int k = 0; k < 8; ++k) pa[k] = 0.f;
    int curg = -1; float cntf = 0.f;
    auto flush = [&]() {
        if (sub == 0) {
#pragma unroll
            for (int k = 0; k < 8; ++k)
                atomicAdd(&g_acc[(size_t)curg * F_HID + q * 8 + k], pa[k]);
            if (lane == 0) atomicAdd(&g_cnt[curg], cntf);
        }
    };
    for (int n = 0; n < NPW; ++n) {
        int i = i0 + n;
        if (i >= N_NODES) break;
        float a[8];
#pragma unroll
        for (int k = 0; k < 8; ++k) a[k] = 0.f;
        int j = offsets[i];
        int e1 = j + ((degs[i] + 15) & ~15);
        for (; j < e1; j += 16) {
            uint2 w = *(const uint2*)&csr[j + 4 * sub];
            int s0 = w.x & 0xffff, s1 = w.x >> 16;
            int s2 = w.y & 0xffff, s3 = w.y >> 16;
            uint4 r0 = hb4[(size_t)s0 * 16 + q];
            uint4 r1 = hb4[(size_t)s1 * 16 + q];
            uint4 r2 = hb4[(size_t)s2 * 16 + q];
            uint4 r3 = hb4[(size_t)s3 * 16 + q];
            acc8(a, r0); acc8(a, r1); acc8(a, r2); acc8(a, r3);
        }
#pragma unroll
        for (int k = 0; k < 8; ++k) a[k] += __shfl_xor(a[k], 16, 64);
#pragma unroll
        for (int k = 0; k < 8; ++k) a[k] += __shfl_xor(a[k], 32, 64);
        uint4 su = hb4[(size_t)i * 16 + q];   // self: weight 1 in scaled domain
        acc8(a, su);
        float dii = dis[i];
        int g = batch[i];
        if (g != curg) {
            if (curg >= 0) flush();
            curg = g; cntf = 0.f;
#pragma unroll
            for (int k = 0; k < 8; ++k) pa[k] = 0.f;
        }
#pragma unroll
        for (int k = 0; k < 8; ++k) pa[k] += a[k] * dii;
        cntf += 1.f;
    }
    if (curg >= 0) flush();
}

// ---------------------------------------------------------------------------
// K7: fused graph head: g2 = (g_acc/cnt)@W2 + b2; g_hid = relu(g2@Wm1+bm1);
// out = g_hid@Wm2 + bm2.  One block per graph, 512 threads.
__global__ __launch_bounds__(512) void fused_mlp(const float* __restrict__ g_acc,
                                                 const float* __restrict__ g_cnt,
                                                 const float* __restrict__ W2,
                                                 const float* __restrict__ b2,
                                                 const float* __restrict__ Wm1,
                                                 const float* __restrict__ bm1,
                                                 const float* __restrict__ Wm2,
                                                 const float* __restrict__ bm2,
                                                 float* __restrict__ out) {
    __shared__ float pool_row[F_HID];
    __shared__ float g2row[F_HID];
    __shared__ float hid[N_HID];
    int g = blockIdx.x;
    int t = threadIdx.x;              // 0..511
    if (t < F_HID) {
        float c = g_cnt[g];
        pool_row[t] = g_acc[(size_t)g * F_HID + t] / fmaxf(c, 1.0f);
    }
    __syncthreads();
    if (t < F_HID) {
        float acc = b2[t];
        for (int k = 0; k < F_HID; ++k) acc += pool_row[k] * W2[(size_t)k * F_HID + t];
        g2row[t] = acc;
    }
    __syncthreads();
    {
        float acc = bm1[t];
        for (int k = 0; k < F_HID; ++k) acc += g2row[k] * Wm1[(size_t)k * N_HID + t];
        hid[t] = fmaxf(acc, 0.f);
    }
    __syncthreads();
    if (t < N_OUT) {
        float acc = bm2[t];
        for (int k = 0; k < N_HID; ++k) acc += hid[k] * Wm2[(size_t)k * N_OUT + t];
        out[(size_t)g * N_OUT + t] = acc;
    }
}

// ---------------------------------------------------------------------------
extern "C" void kernel_launch(void* const* d_in, const int* in_sizes, int n_in,
                              void* d_out, int out_size, void* d_ws, size_t ws_size,
                              hipStream_t stream) {
    const float* x   = (const float*)d_in[0];
    const int* ei    = (const int*)d_in[1];     // [2, E] int32
    const int* batch = (const int*)d_in[2];
    const float* W0 = (const float*)d_in[3];  const float* b0 = (const float*)d_in[4];
    const float* W1 = (const float*)d_in[5];  const float* b1 = (const float*)d_in[6];
    const float* W2 = (const float*)d_in[7];  const float* b2 = (const float*)d_in[8];
    const float* Wm1 = (const float*)d_in[9];  const float* bm1 = (const float*)d_in[10];
    const float* Wm2 = (const float*)d_in[11]; const float* bm2 = (const float*)d_in[12];

    // bump allocator on d_ws, 256B-aligned slots
    char* p = (char*)d_ws;
    auto alloc = [&](size_t bytes) -> char* {
        char* r = p;
        p += (bytes + 255) & ~(size_t)255;
        return r;
    };
    // zero-init region (contiguous in allocation order)
    int*   bucketCur = (int*)alloc(NBKT * 4);
    float* g_acc  = (float*)alloc((size_t)N_GRAPHS * F_HID * 4);
    float* g_cnt  = (float*)alloc(N_GRAPHS * 4);
    size_t zero_bytes = (size_t)(p - (char*)bucketCur);
    // rest
    unsigned int* binned = (unsigned int*)alloc((size_t)NBKT * BKT_S * 4);
    int*   offsets = (int*)alloc((size_t)N_NODES * 4);
    int*   degs    = (int*)alloc((size_t)N_NODES * 4);
    float* dis     = (float*)alloc((size_t)N_NODES * 4);
    unsigned short* csr = (unsigned short*)alloc((size_t)NBKT * BKT_CAP * 2 + 32);
    unsigned int* xb     = (unsigned int*)alloc((size_t)N_PAD * F_IN / 2 * 4);   // bf16 x' (dis-scaled) + zero row
    unsigned int* axb    = (unsigned int*)alloc((size_t)N_PAD * F_IN / 2 * 4);   // bf16 Âx (plain)
    unsigned int* h_tmpb = (unsigned int*)alloc((size_t)N_PAD * F_HID / 2 * 4);  // bf16 (dis-scaled) + zero pad
    unsigned int* h_bb   = (unsigned int*)alloc((size_t)N_PAD * F_HID / 2 * 4);  // bf16 (dis-scaled) + zero row
    unsigned short* W0Tb = (unsigned short*)alloc((size_t)128 * F_IN * 2);
    unsigned short* W1Tb = (unsigned short*)alloc((size_t)128 * F_HID * 2);
    (void)ws_size; (void)in_sizes; (void)n_in; (void)out_size;

    (void)hipMemsetAsync(bucketCur, 0, zero_bytes, stream);

    // CSR construction: privatized binning -> per-bucket deg+scatter (fixed csrBase)
    bin_edges<<<NBIN_BLK, 256, 0, stream>>>(ei, bucketCur, binned);
    deg_scatter<<<NBKT, 256, 0, stream>>>(binned, bucketCur, degs, dis, offsets, csr);

    const int NCVT = N_NODES * F_IN / 4 + (F_IN + F_HID) * 128;
    cvt_all<<<(NCVT + 255) / 256, 256, 0, stream>>>(x, dis, xb, W0, W0Tb, W1, W1Tb);

    int agg_grid = N_NODES / 4 + 1;            // 12501: last block writes zero rows
    int mfma_grid = N_PAD / 64;                // 782 blocks

    // layer 0+1 front: axb = bf16(Â x); h_tmpb = bf16(dis * (relu(axb@W0+b0) @ W1))
    aggregate_xb<<<agg_grid, 256, 0, stream>>>((const uint4*)xb, x, offsets, degs, csr, dis, axb);
    gemm01_mfma<<<mfma_grid, 256, 0, stream>>>(
        (const unsigned short*)axb, W0Tb, b0, W1Tb, dis, h_tmpb, N_NODES);
    // layer 1 back: h_bb = bf16(dis * relu(Â h_tmp + b1))
    aggregate128b<true, true, true><<<agg_grid, 256, 0, stream>>>(
        (const uint4*)h_tmpb, offsets, degs, csr, dis, b1, h_bb);
    // layer 2 (commuted) + pooling fused
    aggregate_pool<<<(N_NODES + 15) / 16, 256, 0, stream>>>(
        (const uint4*)h_bb, offsets, degs, csr, dis, batch, g_acc, g_cnt);

    // fused (W2 + MLP) head
    fused_mlp<<<N_GRAPHS, 512, 0, stream>>>(g_acc, g_cnt, W2, b2, Wm1, bm1, Wm2, bm2,
                                            (float*)d_out);
}

// Round 3
// 248.187 us; speedup vs baseline: 1.2056x; 1.2056x over previous
//
#include <hip/hip_runtime.h>
#include <hip/hip_bf16.h>
#include <math.h>
#include <stdint.h>

#define N_NODES 50000
#define N_PAD   50048   // padded rows for MFMA tile overrun (row 50000 = zero/dummy row)
#define N_EDGES 800000
#define N_GRAPHS 256
#define F_IN 64
#define F_HID 128
#define N_HID 512
#define N_OUT 256

#define NBKT   196           // buckets of 256 nodes (dst >> 8)
#define BKT_S  6144          // per-bucket binned capacity (expected 4082, +32 sigma)
#define BKT_CAP 8192         // fixed per-bucket CSR capacity (expected 5900, +18 sigma)
#define EPB    3328          // edges per bin_edges block (13 * 256)
#define NBIN_BLK ((N_EDGES + EPB - 1) / EPB)   // 241
#define DUMMY_NODE N_NODES   // zero row index for CSR pad slots

using bf16x8 = __attribute__((ext_vector_type(8))) short;   // MFMA A/B frag (4 VGPRs)
using f32x4  = __attribute__((ext_vector_type(4))) float;   // MFMA C/D frag

// pack two fp32 into a uint holding two bf16 (RNE); low16 = a, high16 = b
__device__ __forceinline__ unsigned int bf16pair(float a, float b) {
    unsigned int ua = __float_as_uint(a);
    unsigned int ub = __float_as_uint(b);
    ua += 0x7fffu + ((ua >> 16) & 1u);
    ub += 0x7fffu + ((ub >> 16) & 1u);
    return (ua >> 16) | (ub & 0xffff0000u);
}
__device__ __forceinline__ unsigned short bf16one(float a) {
    unsigned int ua = __float_as_uint(a);
    ua += 0x7fffu + ((ua >> 16) & 1u);
    return (unsigned short)(ua >> 16);
}
__device__ __forceinline__ float bf16lo(unsigned int u) { return __uint_as_float(u << 16); }
__device__ __forceinline__ float bf16hi(unsigned int u) { return __uint_as_float(u & 0xffff0000u); }

// accumulate 8 bf16 features from a uint4 into a[0..7]
__device__ __forceinline__ void acc8(float* a, uint4 r) {
    a[0] += bf16lo(r.x);  a[1] += bf16hi(r.x);
    a[2] += bf16lo(r.y);  a[3] += bf16hi(r.y);
    a[4] += bf16lo(r.z);  a[5] += bf16hi(r.z);
    a[6] += bf16lo(r.w);  a[7] += bf16hi(r.w);
}

// ---------------------------------------------------------------------------
// K0 (merged): xb'[s] = bf16(dis[s] * x[s]) + zero pad row; both weight tables
// fp32 [K][128] -> bf16 [128][K] in the same dispatch.
__global__ void cvt_all(const float* __restrict__ in, const float* __restrict__ dis,
                        unsigned int* __restrict__ xb,
                        const float* __restrict__ W0, unsigned short* __restrict__ W0Tb,
                        const float* __restrict__ W1, unsigned short* __restrict__ W1Tb) {
    const int NX = N_NODES * F_IN / 4;          // 800000 float4 slots
    int idx = blockIdx.x * blockDim.x + threadIdx.x;
    if (idx < NX) {
        int node = idx >> 4;                    // 16 float4 per 64-f row
        float d = dis[node];
        float4 v = ((const float4*)in)[idx];
        ((uint2*)xb)[idx] = make_uint2(bf16pair(d * v.x, d * v.y),
                                       bf16pair(d * v.z, d * v.w));
        if (idx < 16)                            // zero dummy row 50000
            ((uint2*)xb)[(size_t)N_NODES * 16 + idx] = make_uint2(0u, 0u);
    } else {
        int j = idx - NX;
        const int N0 = F_IN * 128;
        const int N1 = F_HID * 128;
        if (j < N0) {
            int k = j >> 7, n = j & 127;
            W0Tb[n * F_IN + k] = bf16one(W0[j]);
        } else if (j < N0 + N1) {
            int jj = j - N0;
            int k = jj >> 7, n = jj & 127;
            W1Tb[n * F_HID + k] = bf16one(W1[jj]);
        }
    }
}

// ---------------------------------------------------------------------------
// K1: bin edges by dst>>8 through LDS staging (privatized binning).
__global__ __launch_bounds__(256) void bin_edges(const int* __restrict__ ei,
                                                 int* __restrict__ bucketCur,
                                                 unsigned int* __restrict__ binned) {
    __shared__ int hist[NBKT];
    __shared__ int lbase[NBKT];
    __shared__ int lcur[NBKT];
    __shared__ int gbase[NBKT];
    __shared__ int scn[256];
    __shared__ unsigned int staging[EPB];
    int tid = threadIdx.x;
    int base = blockIdx.x * EPB;
    int cnt = N_EDGES - base; if (cnt > EPB) cnt = EPB;
    if (tid < NBKT) hist[tid] = 0;
    __syncthreads();
    unsigned int pk[13]; int nk = 0;
#pragma unroll
    for (int u = 0; u < 13; ++u) {
        int e = base + u * 256 + tid;
        if (u * 256 + tid < cnt) {
            unsigned int s = (unsigned int)ei[e];
            unsigned int d = (unsigned int)ei[N_EDGES + e];
            unsigned int b = d >> 8;
            pk[nk++] = (b << 24) | (s << 8) | (d & 255u);
        }
    }
    for (int u = 0; u < nk; ++u) atomicAdd(&hist[pk[u] >> 24], 1);
    __syncthreads();
    // parallel exclusive scan over the 196 bucket counts
    int h = (tid < NBKT) ? hist[tid] : 0;
    scn[tid] = h;
    __syncthreads();
    for (int off = 1; off < 256; off <<= 1) {
        int t = (tid >= off) ? scn[tid - off] : 0;
        __syncthreads();
        scn[tid] += t;
        __syncthreads();
    }
    if (tid < NBKT) { int e0 = scn[tid] - h; lbase[tid] = e0; lcur[tid] = e0; }
    __syncthreads();
    for (int u = 0; u < nk; ++u) {
        int pos = atomicAdd(&lcur[pk[u] >> 24], 1);
        staging[pos] = pk[u];
    }
    if (tid < NBKT && hist[tid] > 0)
        gbase[tid] = atomicAdd(&bucketCur[tid], hist[tid]);
    __syncthreads();
    for (int k = tid; k < cnt; k += 256) {
        unsigned int v = staging[k];
        int b = v >> 24;
        binned[(size_t)b * BKT_S + gbase[b] + (k - lbase[b])] = v & 0xffffffu;
    }
}

// K2 (merged deg + scatter): histogram -> degs/dis/offsets (csrBase fixed at
// b*BKT_CAP: no inter-bucket scan), CSR built in LDS, streamed out coalesced.
__global__ __launch_bounds__(256) void deg_scatter(const unsigned int* __restrict__ binned,
                                                   const int* __restrict__ bucketCur,
                                                   int* __restrict__ degs,
                                                   float* __restrict__ dis,
                                                   int* __restrict__ offsets,
                                                   unsigned short* __restrict__ csr) {
    __shared__ int hist[256];
    __shared__ int tsum[256];
    __shared__ int lcur[256];
    __shared__ uint4 scsr4[BKT_CAP / 8];   // 16 KB CSR staging
    unsigned short* scsr = (unsigned short*)scsr4;
    int b = blockIdx.x;
    int tid = threadIdx.x;
    int node0 = b << 8;
    hist[tid] = 0;
    __syncthreads();
    int cnt = bucketCur[b];
    const unsigned int* bb = &binned[(size_t)b * BKT_S];
    for (int k = tid; k < cnt; k += 256)
        atomicAdd(&hist[bb[k] & 255u], 1);
    __syncthreads();
    int d = hist[tid];
    int s = (d + 15) & ~15;          // align-16 so aggregates run full 16-edge chunks
    tsum[tid] = s;
    __syncthreads();
    for (int off = 1; off < 256; off <<= 1) {
        int t = (tid >= off) ? tsum[tid - off] : 0;
        __syncthreads();
        tsum[tid] += t;
        __syncthreads();
    }
    int excl = tsum[tid] - s;
    int tot = tsum[255];              // multiple of 16
    int csrB = b * BKT_CAP;
    int node = node0 + tid;
    if (node < N_NODES) {
        degs[node] = d;
        dis[node] = rsqrtf((float)(d + 1));
        offsets[node] = csrB + excl;
    }
    lcur[tid] = excl;
    // dummy-fill the aligned LDS region (uint2 = 4 entries; tot % 16 == 0)
    uint2 dv = make_uint2(0xC350C350u, 0xC350C350u);   // 50000 | 50000<<16
    for (int k = tid; k < (tot >> 2); k += 256) ((uint2*)scsr)[k] = dv;
    __syncthreads();
    for (int k = tid; k < cnt; k += 256) {
        unsigned int v = bb[k];
        int dl = v & 255u;
        int p = atomicAdd(&lcur[dl], 1);
        scsr[p] = (unsigned short)(v >> 8);
    }
    __syncthreads();
    for (int k = tid; k < (tot >> 3); k += 256)
        ((uint4*)(csr + csrB))[k] = scsr4[k];
}

// ---------------------------------------------------------------------------
// K4 (fused W0->W1): C0 = relu(axb@W0 + b0) -> bf16 -> per-wave XOR-swizzled
// LDS tile -> h_tmpb = bf16(dis * (C0@W1)). Pad rows write zeros.
__global__ __launch_bounds__(256) void gemm01_mfma(const unsigned short* __restrict__ Ab,
                                                   const unsigned short* __restrict__ W0T,
                                                   const float* __restrict__ b0,
                                                   const unsigned short* __restrict__ W1T,
                                                   const float* __restrict__ disv,
                                                   unsigned int* __restrict__ outb, int M) {
    __shared__ unsigned short tile[4][16 * 128];   // 4 KB per wave, 16 KB total
    int wv = threadIdx.x >> 6;
    int lane = threadIdx.x & 63;
    int m = lane & 15;
    int quad = lane >> 4;
    int row0 = blockIdx.x * 64 + wv * 16;
    char* tl = (char*)&tile[wv][0];
    f32x4 acc[8];
#pragma unroll
    for (int t = 0; t < 8; ++t) acc[t] = (f32x4){0.f, 0.f, 0.f, 0.f};
    // phase 1: K = 64 (axb @ W0)
#pragma unroll
    for (int ks = 0; ks < F_IN; ks += 32) {
        bf16x8 af = *(const bf16x8*)&Ab[(size_t)(row0 + m) * F_IN + ks + quad * 8];
#pragma unroll
        for (int t = 0; t < 8; ++t) {
            bf16x8 bf = *(const bf16x8*)&W0T[(size_t)(t * 16 + m) * F_IN + ks + quad * 8];
            acc[t] = __builtin_amdgcn_mfma_f32_16x16x32_bf16(af, bf, acc[t], 0, 0, 0);
        }
    }
    // epilogue 1: bias + relu -> bf16 -> swizzled LDS (row = quad*4+r, col = t*16+m)
#pragma unroll
    for (int t = 0; t < 8; ++t) {
        int col = t * 16 + m;
        float bcol = b0[col];
#pragma unroll
        for (int r = 0; r < 4; ++r) {
            int row = quad * 4 + r;
            float v = fmaxf(acc[t][r] + bcol, 0.f);
            int byte = (row * 256 + col * 2) ^ ((row & 7) << 4);
            *(unsigned short*)(tl + byte) = bf16one(v);
        }
    }
    __syncthreads();
    // phase 2: K = 128 (C0 @ W1), A-frags from swizzled LDS
#pragma unroll
    for (int t = 0; t < 8; ++t) acc[t] = (f32x4){0.f, 0.f, 0.f, 0.f};
#pragma unroll
    for (int ks = 0; ks < F_HID; ks += 32) {
        int byte = (m * 256 + ks * 2 + quad * 16) ^ ((m & 7) << 4);
        bf16x8 af = *(const bf16x8*)(tl + byte);
#pragma unroll
        for (int t = 0; t < 8; ++t) {
            bf16x8 bf = *(const bf16x8*)&W1T[(size_t)(t * 16 + m) * F_HID + ks + quad * 8];
            acc[t] = __builtin_amdgcn_mfma_f32_16x16x32_bf16(af, bf, acc[t], 0, 0, 0);
        }
    }
    // epilogue 2: dis-scale, pair-write bf16, zero pad rows
    float dr[4];
#pragma unroll
    for (int r = 0; r < 4; ++r) {
        int row = row0 + quad * 4 + r;
        dr[r] = (row < M) ? disv[row] : 0.f;
    }
#pragma unroll
    for (int t = 0; t < 8; ++t) {
        int col = t * 16 + m;
#pragma unroll
        for (int r = 0; r < 4; ++r) {
            float v = acc[t][r] * dr[r];
            float vn = __shfl_xor(v, 1, 64);    // neighbor col's value
            if ((m & 1) == 0) {
                int row = row0 + quad * 4 + r;
                outb[(size_t)row * 64 + (col >> 1)] = (row < M) ? bf16pair(v, vn) : 0u;
            }
        }
    }
}

// ---------------------------------------------------------------------------
// K5a: F=128 aggregate over PRE-SCALED bf16 table. 4 edges/inst, no tail.
template <bool RELU, bool BIAS, bool SCALEOUT>
__global__ __launch_bounds__(256) void aggregate128b(const uint4* __restrict__ hb4,
                                                     const int* __restrict__ offsets,
                                                     const int* __restrict__ degs,
                                                     const unsigned short* __restrict__ csr,
                                                     const float* __restrict__ dis,
                                                     const float* __restrict__ bias,
                                                     unsigned int* __restrict__ outb) {
    int wave = threadIdx.x >> 6;
    int lane = threadIdx.x & 63;
    int i = blockIdx.x * 4 + wave;
    int sub = lane >> 4;              // 0..3: which edge-quad
    int q   = lane & 15;              // uint4 index within the 16-uint4 row
    if (i >= N_NODES) {
        if (i == N_NODES && sub == 0)  // zero dummy row for downstream gathers
            ((uint4*)outb)[(size_t)N_NODES * 16 + q] = make_uint4(0u, 0u, 0u, 0u);
        return;
    }
    float a[8];
#pragma unroll
    for (int k = 0; k < 8; ++k) a[k] = 0.f;
    int j = offsets[i];
    int e1 = j + ((degs[i] + 15) & ~15);
    for (; j < e1; j += 16) {
        uint2 w = *(const uint2*)&csr[j + 4 * sub];
        int s0 = w.x & 0xffff, s1 = w.x >> 16;
        int s2 = w.y & 0xffff, s3 = w.y >> 16;
        uint4 r0 = hb4[(size_t)s0 * 16 + q];
        uint4 r1 = hb4[(size_t)s1 * 16 + q];
        uint4 r2 = hb4[(size_t)s2 * 16 + q];
        uint4 r3 = hb4[(size_t)s3 * 16 + q];
        acc8(a, r0); acc8(a, r1); acc8(a, r2); acc8(a, r3);
    }
#pragma unroll
    for (int k = 0; k < 8; ++k) a[k] += __shfl_xor(a[k], 16, 64);
#pragma unroll
    for (int k = 0; k < 8; ++k) a[k] += __shfl_xor(a[k], 32, 64);
    uint4 su = hb4[(size_t)i * 16 + q];     // self: weight 1 in scaled domain
    acc8(a, su);
    float dii = dis[i];
#pragma unroll
    for (int k = 0; k < 8; ++k) a[k] *= dii;
    if (BIAS) {
        float4 b0 = ((const float4*)bias)[2 * q];
        float4 b1 = ((const float4*)bias)[2 * q + 1];
        a[0] += b0.x; a[1] += b0.y; a[2] += b0.z; a[3] += b0.w;
        a[4] += b1.x; a[5] += b1.y; a[6] += b1.z; a[7] += b1.w;
    }
    if (RELU) {
#pragma unroll
        for (int k = 0; k < 8; ++k) a[k] = fmaxf(a[k], 0.f);
    }
    if (sub == 0) {
        float sc = SCALEOUT ? dii : 1.f;
        ((uint4*)outb)[(size_t)i * 16 + q] =
            make_uint4(bf16pair(sc * a[0], sc * a[1]), bf16pair(sc * a[2], sc * a[3]),
                       bf16pair(sc * a[4], sc * a[5]), bf16pair(sc * a[6], sc * a[7]));
    }
}

// K5b: F=64 aggregate over pre-scaled bf16 x-table. 8 edges/inst, no tail.
__global__ __launch_bounds__(256) void aggregate_xb(const uint4* __restrict__ xb4,
                                                    const float* __restrict__ x,
                                                    const int* __restrict__ offsets,
                                                    const int* __restrict__ degs,
                                                    const unsigned short* __restrict__ csr,
                                                    const float* __restrict__ dis,
                                                    unsigned int* __restrict__ outb) {
    int wave = threadIdx.x >> 6;
    int lane = threadIdx.x & 63;
    int i = blockIdx.x * 4 + wave;
    int sub = lane >> 3;              // 0..7: which edge-pair
    int q   = lane & 7;               // uint4 index within the 8-uint4 row
    if (i >= N_NODES) {
        if (i == N_NODES && sub == 0)
            ((uint4*)outb)[(size_t)N_NODES * 8 + q] = make_uint4(0u, 0u, 0u, 0u);
        return;
    }
    float a[8];
#pragma unroll
    for (int k = 0; k < 8; ++k) a[k] = 0.f;
    int j = offsets[i];
    int e1 = j + ((degs[i] + 15) & ~15);
    for (; j < e1; j += 16) {
        unsigned int w = *(const unsigned int*)&csr[j + 2 * sub];
        int s0 = w & 0xffff, s1 = w >> 16;
        uint4 r0 = xb4[(size_t)s0 * 8 + q];
        uint4 r1 = xb4[(size_t)s1 * 8 + q];
        acc8(a, r0); acc8(a, r1);
    }
#pragma unroll
    for (int k = 0; k < 8; ++k) a[k] += __shfl_xor(a[k], 8, 64);
#pragma unroll
    for (int k = 0; k < 8; ++k) a[k] += __shfl_xor(a[k], 16, 64);
#pragma unroll
    for (int k = 0; k < 8; ++k) a[k] += __shfl_xor(a[k], 32, 64);
    float dii = dis[i];
    float d2 = dii * dii;
    float4 sx0 = ((const float4*)x)[(size_t)i * 16 + 2 * q];       // self in fp32
    float4 sx1 = ((const float4*)x)[(size_t)i * 16 + 2 * q + 1];
    a[0] = dii * a[0] + d2 * sx0.x;  a[1] = dii * a[1] + d2 * sx0.y;
    a[2] = dii * a[2] + d2 * sx0.z;  a[3] = dii * a[3] + d2 * sx0.w;
    a[4] = dii * a[4] + d2 * sx1.x;  a[5] = dii * a[5] + d2 * sx1.y;
    a[6] = dii * a[6] + d2 * sx1.z;  a[7] = dii * a[7] + d2 * sx1.w;
    if (sub == 0)
        ((uint4*)outb)[(size_t)i * 8 + q] =
            make_uint4(bf16pair(a[0], a[1]), bf16pair(a[2], a[3]),
                       bf16pair(a[4], a[5]), bf16pair(a[6], a[7]));
}

// K5c v2: layer-2 aggregate FUSED with mean-pool, group-per-node layout.
// 256 threads = 16 groups x 16 lanes; group g owns node blockIdx*16+g, all 16
// nodes gathered IN PARALLEL (8 independent uint4 gathers in flight per lane,
// no cross-lane reduce). Rows staged in LDS, then pool16-style flush
// (atomics amortized over 16 nodes).
__global__ __launch_bounds__(256) void aggregate_pool(const uint4* __restrict__ hb4,
                                                      const int* __restrict__ offsets,
                                                      const int* __restrict__ degs,
                                                      const unsigned short* __restrict__ csr,
                                                      const float* __restrict__ dis,
                                                      const int* __restrict__ batch,
                                                      float* __restrict__ g_acc,
                                                      float* __restrict__ g_cnt) {
    __shared__ float pool[16][128];   // [node][k*16+q] layout (<=4-way bank conflict)
    int tid = threadIdx.x;
    int grp = tid >> 4;               // 0..15: node within block
    int q   = tid & 15;               // uint4 column (features q*8 .. q*8+7)
    int i = blockIdx.x * 16 + grp;
    float a[8];
#pragma unroll
    for (int k = 0; k < 8; ++k) a[k] = 0.f;
    if (i < N_NODES) {
        int j = offsets[i];
        int e1 = j + ((degs[i] + 15) & ~15);
        for (; j < e1; j += 16) {
            // 16 src indices for this chunk (uniform within the group)
            uint4 w0 = *(const uint4*)&csr[j];
            uint4 w1 = *(const uint4*)&csr[j + 8];
            int s[16];
            s[0] = w0.x & 0xffff;  s[1] = w0.x >> 16;
            s[2] = w0.y & 0xffff;  s[3] = w0.y >> 16;
            s[4] = w0.z & 0xffff;  s[5] = w0.z >> 16;
            s[6] = w0.w & 0xffff;  s[7] = w0.w >> 16;
            s[8] = w1.x & 0xffff;  s[9] = w1.x >> 16;
            s[10] = w1.y & 0xffff; s[11] = w1.y >> 16;
            s[12] = w1.z & 0xffff; s[13] = w1.z >> 16;
            s[14] = w1.w & 0xffff; s[15] = w1.w >> 16;
            uint4 r[8];
#pragma unroll
            for (int u = 0; u < 8; ++u) r[u] = hb4[(size_t)s[u] * 16 + q];
#pragma unroll
            for (int u = 0; u < 8; ++u) acc8(a, r[u]);
#pragma unroll
            for (int u = 0; u < 8; ++u) r[u] = hb4[(size_t)s[8 + u] * 16 + q];
#pragma unroll
            for (int u = 0; u < 8; ++u) acc8(a, r[u]);
        }
        uint4 su = hb4[(size_t)i * 16 + q];   // self: weight 1 in scaled domain
        acc8(a, su);
        float dii = dis[i];
#pragma unroll
        for (int k = 0; k < 8; ++k) a[k] *= dii;
    }
#pragma unroll
    for (int k = 0; k < 8; ++k) pool[grp][k * 16 + q] = a[k];
    __syncthreads();
    // flush phase: 128 threads accumulate the 16 rows, atomics per graph change
    if (tid < 128) {
        int f = tid;                              // feature index
        int lidx = (f & 7) * 16 + (f >> 3);       // LDS index for feature f
        int base = blockIdx.x * 16;
        float acc = 0.f; int cur = -1; float cnt = 0.f;
        for (int n = 0; n < 16; ++n) {
            int i2 = base + n;
            if (i2 >= N_NODES) break;
            int b = batch[i2];
            if (b != cur) {
                if (cur >= 0) {
                    atomicAdd(&g_acc[(size_t)cur * F_HID + f], acc);
                    if (f == 0) atomicAdd(&g_cnt[cur], cnt);
                }
                cur = b; acc = 0.f; cnt = 0.f;
            }
            acc += pool[n][lidx];
            cnt += 1.f;
        }
        if (cur >= 0) {
            atomicAdd(&g_acc[(size_t)cur * F_HID + f], acc);
            if (f == 0) atomicAdd(&g_cnt[cur], cnt);
        }
    }
}

// ---------------------------------------------------------------------------
// K7: fused graph head: g2 = (g_acc/cnt)@W2 + b2; g_hid = relu(g2@Wm1+bm1);
// out = g_hid@Wm2 + bm2.  One block per graph, 512 threads.
__global__ __launch_bounds__(512) void fused_mlp(const float* __restrict__ g_acc,
                                                 const float* __restrict__ g_cnt,
                                                 const float* __restrict__ W2,
                                                 const float* __restrict__ b2,
                                                 const float* __restrict__ Wm1,
                                                 const float* __restrict__ bm1,
                                                 const float* __restrict__ Wm2,
                                                 const float* __restrict__ bm2,
                                                 float* __restrict__ out) {
    __shared__ float pool_row[F_HID];
    __shared__ float g2row[F_HID];
    __shared__ float hid[N_HID];
    int g = blockIdx.x;
    int t = threadIdx.x;              // 0..511
    if (t < F_HID) {
        float c = g_cnt[g];
        pool_row[t] = g_acc[(size_t)g * F_HID + t] / fmaxf(c, 1.0f);
    }
    __syncthreads();
    if (t < F_HID) {
        float acc = b2[t];
        for (int k = 0; k < F_HID; ++k) acc += pool_row[k] * W2[(size_t)k * F_HID + t];
        g2row[t] = acc;
    }
    __syncthreads();
    {
        float acc = bm1[t];
        for (int k = 0; k < F_HID; ++k) acc += g2row[k] * Wm1[(size_t)k * N_HID + t];
        hid[t] = fmaxf(acc, 0.f);
    }
    __syncthreads();
    if (t < N_OUT) {
        float acc = bm2[t];
        for (int k = 0; k < N_HID; ++k) acc += hid[k] * Wm2[(size_t)k * N_OUT + t];
        out[(size_t)g * N_OUT + t] = acc;
    }
}

// ---------------------------------------------------------------------------
extern "C" void kernel_launch(void* const* d_in, const int* in_sizes, int n_in,
                              void* d_out, int out_size, void* d_ws, size_t ws_size,
                              hipStream_t stream) {
    const float* x   = (const float*)d_in[0];
    const int* ei    = (const int*)d_in[1];     // [2, E] int32
    const int* batch = (const int*)d_in[2];
    const float* W0 = (const float*)d_in[3];  const float* b0 = (const float*)d_in[4];
    const float* W1 = (const float*)d_in[5];  const float* b1 = (const float*)d_in[6];
    const float* W2 = (const float*)d_in[7];  const float* b2 = (const float*)d_in[8];
    const float* Wm1 = (const float*)d_in[9];  const float* bm1 = (const float*)d_in[10];
    const float* Wm2 = (const float*)d_in[11]; const float* bm2 = (const float*)d_in[12];

    // bump allocator on d_ws, 256B-aligned slots
    char* p = (char*)d_ws;
    auto alloc = [&](size_t bytes) -> char* {
        char* r = p;
        p += (bytes + 255) & ~(size_t)255;
        return r;
    };
    // zero-init region (contiguous in allocation order)
    int*   bucketCur = (int*)alloc(NBKT * 4);
    float* g_acc  = (float*)alloc((size_t)N_GRAPHS * F_HID * 4);
    float* g_cnt  = (float*)alloc(N_GRAPHS * 4);
    size_t zero_bytes = (size_t)(p - (char*)bucketCur);
    // rest
    unsigned int* binned = (unsigned int*)alloc((size_t)NBKT * BKT_S * 4);
    int*   offsets = (int*)alloc((size_t)N_NODES * 4);
    int*   degs    = (int*)alloc((size_t)N_NODES * 4);
    float* dis     = (float*)alloc((size_t)N_NODES * 4);
    unsigned short* csr = (unsigned short*)alloc((size_t)NBKT * BKT_CAP * 2 + 32);
    unsigned int* xb     = (unsigned int*)alloc((size_t)N_PAD * F_IN / 2 * 4);   // bf16 x' (dis-scaled) + zero row
    unsigned int* axb    = (unsigned int*)alloc((size_t)N_PAD * F_IN / 2 * 4);   // bf16 Âx (plain)
    unsigned int* h_tmpb = (unsigned int*)alloc((size_t)N_PAD * F_HID / 2 * 4);  // bf16 (dis-scaled) + zero pad
    unsigned int* h_bb   = (unsigned int*)alloc((size_t)N_PAD * F_HID / 2 * 4);  // bf16 (dis-scaled) + zero row
    unsigned short* W0Tb = (unsigned short*)alloc((size_t)128 * F_IN * 2);
    unsigned short* W1Tb = (unsigned short*)alloc((size_t)128 * F_HID * 2);
    (void)ws_size; (void)in_sizes; (void)n_in; (void)out_size;

    (void)hipMemsetAsync(bucketCur, 0, zero_bytes, stream);

    // CSR construction: privatized binning -> per-bucket deg+scatter (fixed csrBase)
    bin_edges<<<NBIN_BLK, 256, 0, stream>>>(ei, bucketCur, binned);
    deg_scatter<<<NBKT, 256, 0, stream>>>(binned, bucketCur, degs, dis, offsets, csr);

    const int NCVT = N_NODES * F_IN / 4 + (F_IN + F_HID) * 128;
    cvt_all<<<(NCVT + 255) / 256, 256, 0, stream>>>(x, dis, xb, W0, W0Tb, W1, W1Tb);

    int agg_grid = N_NODES / 4 + 1;            // 12501: last block writes zero rows
    int mfma_grid = N_PAD / 64;                // 782 blocks

    // layer 0+1 front: axb = bf16(Â x); h_tmpb = bf16(dis * (relu(axb@W0+b0) @ W1))
    aggregate_xb<<<agg_grid, 256, 0, stream>>>((const uint4*)xb, x, offsets, degs, csr, dis, axb);
    gemm01_mfma<<<mfma_grid, 256, 0, stream>>>(
        (const unsigned short*)axb, W0Tb, b0, W1Tb, dis, h_tmpb, N_NODES);
    // layer 1 back: h_bb = bf16(dis * relu(Â h_tmp + b1))
    aggregate128b<true, true, true><<<agg_grid, 256, 0, stream>>>(
        (const uint4*)h_tmpb, offsets, degs, csr, dis, b1, h_bb);
    // layer 2 (commuted) + pooling fused, group-per-node
    aggregate_pool<<<(N_NODES + 15) / 16, 256, 0, stream>>>(
        (const uint4*)h_bb, offsets, degs, csr, dis, batch, g_acc, g_cnt);

    // fused (W2 + MLP) head
    fused_mlp<<<N_GRAPHS, 512, 0, stream>>>(g_acc, g_cnt, W2, b2, Wm1, bm1, Wm2, bm2,
                                            (float*)d_out);
}

// Round 4
// 239.689 us; speedup vs baseline: 1.2484x; 1.0355x over previous
//
#include <hip/hip_runtime.h>
#include <hip/hip_bf16.h>
#include <math.h>
#include <stdint.h>

#define N_NODES 50000
#define N_PAD   50048   // padded rows for MFMA tile overrun (row 50000 = zero/dummy row)
#define N_EDGES 800000
#define N_GRAPHS 256
#define F_IN 64
#define F_HID 128
#define N_HID 512
#define N_OUT 256

#define NBKT   196           // buckets of 256 nodes (dst >> 8)
#define BKT_S  6144          // per-bucket binned capacity (expected 4082, +32 sigma)
#define BKT_CAP 8192         // fixed per-bucket CSR capacity (expected 5900, +18 sigma)
#define EPB    3328          // edges per bin_edges block (13 * 256)
#define NBIN_BLK ((N_EDGES + EPB - 1) / EPB)   // 241
#define DUMMY_NODE N_NODES   // zero row index for CSR pad slots

using bf16x8 = __attribute__((ext_vector_type(8))) short;   // MFMA A/B frag (4 VGPRs)
using f32x4  = __attribute__((ext_vector_type(4))) float;   // MFMA C/D frag

// pack two fp32 into a uint holding two bf16 (RNE); low16 = a, high16 = b
__device__ __forceinline__ unsigned int bf16pair(float a, float b) {
    unsigned int ua = __float_as_uint(a);
    unsigned int ub = __float_as_uint(b);
    ua += 0x7fffu + ((ua >> 16) & 1u);
    ub += 0x7fffu + ((ub >> 16) & 1u);
    return (ua >> 16) | (ub & 0xffff0000u);
}
__device__ __forceinline__ unsigned short bf16one(float a) {
    unsigned int ua = __float_as_uint(a);
    ua += 0x7fffu + ((ua >> 16) & 1u);
    return (unsigned short)(ua >> 16);
}
__device__ __forceinline__ float bf16lo(unsigned int u) { return __uint_as_float(u << 16); }
__device__ __forceinline__ float bf16hi(unsigned int u) { return __uint_as_float(u & 0xffff0000u); }

// accumulate 8 bf16 features from a uint4 into a[0..7]
__device__ __forceinline__ void acc8(float* a, uint4 r) {
    a[0] += bf16lo(r.x);  a[1] += bf16hi(r.x);
    a[2] += bf16lo(r.y);  a[3] += bf16hi(r.y);
    a[4] += bf16lo(r.z);  a[5] += bf16hi(r.z);
    a[6] += bf16lo(r.w);  a[7] += bf16hi(r.w);
}

// unpack 16 csr entries (uniform within a lane group; cached/broadcast loads)
__device__ __forceinline__ void csr16(const unsigned short* __restrict__ csr, int j, int* s) {
    uint4 w0 = *(const uint4*)&csr[j];
    uint4 w1 = *(const uint4*)&csr[j + 8];
    s[0] = w0.x & 0xffff;  s[1] = w0.x >> 16;
    s[2] = w0.y & 0xffff;  s[3] = w0.y >> 16;
    s[4] = w0.z & 0xffff;  s[5] = w0.z >> 16;
    s[6] = w0.w & 0xffff;  s[7] = w0.w >> 16;
    s[8] = w1.x & 0xffff;  s[9] = w1.x >> 16;
    s[10] = w1.y & 0xffff; s[11] = w1.y >> 16;
    s[12] = w1.z & 0xffff; s[13] = w1.z >> 16;
    s[14] = w1.w & 0xffff; s[15] = w1.w >> 16;
}

// ---------------------------------------------------------------------------
// K0 (merged): xb'[s] = bf16(dis[s] * x[s]) + zero pad row; both weight tables
// fp32 [K][128] -> bf16 [128][K] in the same dispatch.
__global__ void cvt_all(const float* __restrict__ in, const float* __restrict__ dis,
                        unsigned int* __restrict__ xb,
                        const float* __restrict__ W0, unsigned short* __restrict__ W0Tb,
                        const float* __restrict__ W1, unsigned short* __restrict__ W1Tb) {
    const int NX = N_NODES * F_IN / 4;          // 800000 float4 slots
    int idx = blockIdx.x * blockDim.x + threadIdx.x;
    if (idx < NX) {
        int node = idx >> 4;                    // 16 float4 per 64-f row
        float d = dis[node];
        float4 v = ((const float4*)in)[idx];
        ((uint2*)xb)[idx] = make_uint2(bf16pair(d * v.x, d * v.y),
                                       bf16pair(d * v.z, d * v.w));
        if (idx < 16)                            // zero dummy row 50000
            ((uint2*)xb)[(size_t)N_NODES * 16 + idx] = make_uint2(0u, 0u);
    } else {
        int j = idx - NX;
        const int N0 = F_IN * 128;
        const int N1 = F_HID * 128;
        if (j < N0) {
            int k = j >> 7, n = j & 127;
            W0Tb[n * F_IN + k] = bf16one(W0[j]);
        } else if (j < N0 + N1) {
            int jj = j - N0;
            int k = jj >> 7, n = jj & 127;
            W1Tb[n * F_HID + k] = bf16one(W1[jj]);
        }
    }
}

// ---------------------------------------------------------------------------
// K1: bin edges by dst>>8 through LDS staging (privatized binning).
__global__ __launch_bounds__(256) void bin_edges(const int* __restrict__ ei,
                                                 int* __restrict__ bucketCur,
                                                 unsigned int* __restrict__ binned) {
    __shared__ int hist[NBKT];
    __shared__ int lbase[NBKT];
    __shared__ int lcur[NBKT];
    __shared__ int gbase[NBKT];
    __shared__ int scn[256];
    __shared__ unsigned int staging[EPB];
    int tid = threadIdx.x;
    int base = blockIdx.x * EPB;
    int cnt = N_EDGES - base; if (cnt > EPB) cnt = EPB;
    if (tid < NBKT) hist[tid] = 0;
    __syncthreads();
    unsigned int pk[13]; int nk = 0;
#pragma unroll
    for (int u = 0; u < 13; ++u) {
        int e = base + u * 256 + tid;
        if (u * 256 + tid < cnt) {
            unsigned int s = (unsigned int)ei[e];
            unsigned int d = (unsigned int)ei[N_EDGES + e];
            unsigned int b = d >> 8;
            pk[nk++] = (b << 24) | (s << 8) | (d & 255u);
        }
    }
    for (int u = 0; u < nk; ++u) atomicAdd(&hist[pk[u] >> 24], 1);
    __syncthreads();
    // parallel exclusive scan over the 196 bucket counts
    int h = (tid < NBKT) ? hist[tid] : 0;
    scn[tid] = h;
    __syncthreads();
    for (int off = 1; off < 256; off <<= 1) {
        int t = (tid >= off) ? scn[tid - off] : 0;
        __syncthreads();
        scn[tid] += t;
        __syncthreads();
    }
    if (tid < NBKT) { int e0 = scn[tid] - h; lbase[tid] = e0; lcur[tid] = e0; }
    __syncthreads();
    for (int u = 0; u < nk; ++u) {
        int pos = atomicAdd(&lcur[pk[u] >> 24], 1);
        staging[pos] = pk[u];
    }
    if (tid < NBKT && hist[tid] > 0)
        gbase[tid] = atomicAdd(&bucketCur[tid], hist[tid]);
    __syncthreads();
    for (int k = tid; k < cnt; k += 256) {
        unsigned int v = staging[k];
        int b = v >> 24;
        binned[(size_t)b * BKT_S + gbase[b] + (k - lbase[b])] = v & 0xffffffu;
    }
}

// K2 (merged deg + scatter): histogram -> degs/dis/offsets (csrBase fixed at
// b*BKT_CAP: no inter-bucket scan), CSR built in LDS, streamed out coalesced.
__global__ __launch_bounds__(256) void deg_scatter(const unsigned int* __restrict__ binned,
                                                   const int* __restrict__ bucketCur,
                                                   int* __restrict__ degs,
                                                   float* __restrict__ dis,
                                                   int* __restrict__ offsets,
                                                   unsigned short* __restrict__ csr) {
    __shared__ int hist[256];
    __shared__ int tsum[256];
    __shared__ int lcur[256];
    __shared__ uint4 scsr4[BKT_CAP / 8];   // 16 KB CSR staging
    unsigned short* scsr = (unsigned short*)scsr4;
    int b = blockIdx.x;
    int tid = threadIdx.x;
    int node0 = b << 8;
    hist[tid] = 0;
    __syncthreads();
    int cnt = bucketCur[b];
    const unsigned int* bb = &binned[(size_t)b * BKT_S];
    for (int k = tid; k < cnt; k += 256)
        atomicAdd(&hist[bb[k] & 255u], 1);
    __syncthreads();
    int d = hist[tid];
    int s = (d + 15) & ~15;          // align-16 so aggregates run full 16-edge chunks
    tsum[tid] = s;
    __syncthreads();
    for (int off = 1; off < 256; off <<= 1) {
        int t = (tid >= off) ? tsum[tid - off] : 0;
        __syncthreads();
        tsum[tid] += t;
        __syncthreads();
    }
    int excl = tsum[tid] - s;
    int tot = tsum[255];              // multiple of 16
    int csrB = b * BKT_CAP;
    int node = node0 + tid;
    if (node < N_NODES) {
        degs[node] = d;
        dis[node] = rsqrtf((float)(d + 1));
        offsets[node] = csrB + excl;
    }
    lcur[tid] = excl;
    // dummy-fill the aligned LDS region (uint2 = 4 entries; tot % 16 == 0)
    uint2 dv = make_uint2(0xC350C350u, 0xC350C350u);   // 50000 | 50000<<16
    for (int k = tid; k < (tot >> 2); k += 256) ((uint2*)scsr)[k] = dv;
    __syncthreads();
    for (int k = tid; k < cnt; k += 256) {
        unsigned int v = bb[k];
        int dl = v & 255u;
        int p = atomicAdd(&lcur[dl], 1);
        scsr[p] = (unsigned short)(v >> 8);
    }
    __syncthreads();
    for (int k = tid; k < (tot >> 3); k += 256)
        ((uint4*)(csr + csrB))[k] = scsr4[k];
}

// ---------------------------------------------------------------------------
// K4 v2 (fused L0-aggregate + W0 GEMM + W1 GEMM): per 64-row block:
//   phase A: gather-aggregate axb rows directly into XOR-swizzled LDS A-tile
//            (32 groups x 8 lanes, all 64 nodes in parallel, no shuffles)
//   phase B: C0 = relu(A@W0 + b0) -> bf16 -> per-wave swizzled LDS tile
//            -> h_tmpb = bf16(dis * (C0@W1)). Pad rows write zeros.
__global__ __launch_bounds__(256) void agg_gemm01(const uint4* __restrict__ xb4,
                                                  const float* __restrict__ x,
                                                  const int* __restrict__ offsets,
                                                  const int* __restrict__ degs,
                                                  const unsigned short* __restrict__ csr,
                                                  const float* __restrict__ dis,
                                                  const unsigned short* __restrict__ W0T,
                                                  const float* __restrict__ b0,
                                                  const unsigned short* __restrict__ W1T,
                                                  unsigned int* __restrict__ outb, int M) {
    __shared__ unsigned short atile[64 * 64];      // 8 KB A tile (XOR swizzled rows)
    __shared__ unsigned short tile[4][16 * 128];   // 16 KB C0 per-wave tiles
    int tid = threadIdx.x;
    int row0 = blockIdx.x * 64;
    char* at = (char*)atile;
    // ---- phase A: aggregate 64 nodes ----
    {
        int grp = tid >> 3;              // 0..31
        int q   = tid & 7;               // uint4 col (features q*8..q*8+7)
#pragma unroll
        for (int pass = 0; pass < 2; ++pass) {
            int node = grp + pass * 32;  // 0..63 within tile
            int i = row0 + node;
            float a[8];
#pragma unroll
            for (int k = 0; k < 8; ++k) a[k] = 0.f;
            if (i < N_NODES) {
                int j = offsets[i];
                int e1 = j + ((degs[i] + 15) & ~15);
                for (; j < e1; j += 16) {
                    int s[16];
                    csr16(csr, j, s);
                    uint4 r[8];
#pragma unroll
                    for (int u = 0; u < 8; ++u) r[u] = xb4[(size_t)s[u] * 8 + q];
#pragma unroll
                    for (int u = 0; u < 8; ++u) acc8(a, r[u]);
#pragma unroll
                    for (int u = 0; u < 8; ++u) r[u] = xb4[(size_t)s[8 + u] * 8 + q];
#pragma unroll
                    for (int u = 0; u < 8; ++u) acc8(a, r[u]);
                }
                float dii = dis[i];
                float d2 = dii * dii;
                float4 sx0 = ((const float4*)x)[(size_t)i * 16 + 2 * q];   // self fp32
                float4 sx1 = ((const float4*)x)[(size_t)i * 16 + 2 * q + 1];
                a[0] = dii * a[0] + d2 * sx0.x;  a[1] = dii * a[1] + d2 * sx0.y;
                a[2] = dii * a[2] + d2 * sx0.z;  a[3] = dii * a[3] + d2 * sx0.w;
                a[4] = dii * a[4] + d2 * sx1.x;  a[5] = dii * a[5] + d2 * sx1.y;
                a[6] = dii * a[6] + d2 * sx1.z;  a[7] = dii * a[7] + d2 * sx1.w;
            }
            int byte = (node * 128 + q * 16) ^ ((node & 7) << 4);
            *(uint4*)(at + byte) =
                make_uint4(bf16pair(a[0], a[1]), bf16pair(a[2], a[3]),
                           bf16pair(a[4], a[5]), bf16pair(a[6], a[7]));
        }
    }
    __syncthreads();
    // ---- phase B: dual GEMM ----
    int wv = tid >> 6;
    int lane = tid & 63;
    int m = lane & 15;
    int quad = lane >> 4;
    int wrow0 = row0 + wv * 16;
    char* tl = (char*)&tile[wv][0];
    f32x4 acc[8];
#pragma unroll
    for (int t = 0; t < 8; ++t) acc[t] = (f32x4){0.f, 0.f, 0.f, 0.f};
    // phase 1: K = 64 (A @ W0), A-frags from swizzled LDS A-tile
#pragma unroll
    for (int ks = 0; ks < F_IN; ks += 32) {
        int abyte = ((wv * 16 + m) * 128 + (ks + quad * 8) * 2) ^ ((m & 7) << 4);
        bf16x8 af = *(const bf16x8*)(at + abyte);
#pragma unroll
        for (int t = 0; t < 8; ++t) {
            bf16x8 bf = *(const bf16x8*)&W0T[(size_t)(t * 16 + m) * F_IN + ks + quad * 8];
            acc[t] = __builtin_amdgcn_mfma_f32_16x16x32_bf16(af, bf, acc[t], 0, 0, 0);
        }
    }
    // epilogue 1: bias + relu -> bf16 -> swizzled LDS (row = quad*4+r, col = t*16+m)
#pragma unroll
    for (int t = 0; t < 8; ++t) {
        int col = t * 16 + m;
        float bcol = b0[col];
#pragma unroll
        for (int r = 0; r < 4; ++r) {
            int row = quad * 4 + r;
            float v = fmaxf(acc[t][r] + bcol, 0.f);
            int byte = (row * 256 + col * 2) ^ ((row & 7) << 4);
            *(unsigned short*)(tl + byte) = bf16one(v);
        }
    }
    __syncthreads();
    // phase 2: K = 128 (C0 @ W1), A-frags from swizzled LDS
#pragma unroll
    for (int t = 0; t < 8; ++t) acc[t] = (f32x4){0.f, 0.f, 0.f, 0.f};
#pragma unroll
    for (int ks = 0; ks < F_HID; ks += 32) {
        int byte = (m * 256 + ks * 2 + quad * 16) ^ ((m & 7) << 4);
        bf16x8 af = *(const bf16x8*)(tl + byte);
#pragma unroll
        for (int t = 0; t < 8; ++t) {
            bf16x8 bf = *(const bf16x8*)&W1T[(size_t)(t * 16 + m) * F_HID + ks + quad * 8];
            acc[t] = __builtin_amdgcn_mfma_f32_16x16x32_bf16(af, bf, acc[t], 0, 0, 0);
        }
    }
    // epilogue 2: dis-scale, pair-write bf16, zero pad rows
    float dr[4];
#pragma unroll
    for (int r = 0; r < 4; ++r) {
        int row = wrow0 + quad * 4 + r;
        dr[r] = (row < M) ? dis[row] : 0.f;
    }
#pragma unroll
    for (int t = 0; t < 8; ++t) {
        int col = t * 16 + m;
#pragma unroll
        for (int r = 0; r < 4; ++r) {
            float v = acc[t][r] * dr[r];
            float vn = __shfl_xor(v, 1, 64);    // neighbor col's value
            if ((m & 1) == 0) {
                int row = wrow0 + quad * 4 + r;
                outb[(size_t)row * 64 + (col >> 1)] = (row < M) ? bf16pair(v, vn) : 0u;
            }
        }
    }
}

// ---------------------------------------------------------------------------
// K5a v2: F=128 aggregate, group-per-node (16 groups x 16 lanes). Lane q owns
// uint4 column q end-to-end: 16 independent gathers in flight per chunk, no
// cross-lane shuffles, coalesced 256 B per row, direct uint4 store.
template <bool RELU, bool BIAS, bool SCALEOUT>
__global__ __launch_bounds__(256) void aggregate128g(const uint4* __restrict__ hb4,
                                                     const int* __restrict__ offsets,
                                                     const int* __restrict__ degs,
                                                     const unsigned short* __restrict__ csr,
                                                     const float* __restrict__ dis,
                                                     const float* __restrict__ bias,
                                                     unsigned int* __restrict__ outb) {
    int tid = threadIdx.x;
    int grp = tid >> 4;               // 0..15: node within block
    int q   = tid & 15;               // uint4 column (features q*8..q*8+7)
    int i = blockIdx.x * 16 + grp;
    if (i >= N_NODES) {
        if (i == N_NODES)             // zero dummy row for downstream gathers
            ((uint4*)outb)[(size_t)N_NODES * 16 + q] = make_uint4(0u, 0u, 0u, 0u);
        return;
    }
    float a[8];
#pragma unroll
    for (int k = 0; k < 8; ++k) a[k] = 0.f;
    int j = offsets[i];
    int e1 = j + ((degs[i] + 15) & ~15);
    for (; j < e1; j += 16) {
        int s[16];
        csr16(csr, j, s);
        uint4 r[8];
#pragma unroll
        for (int u = 0; u < 8; ++u) r[u] = hb4[(size_t)s[u] * 16 + q];
#pragma unroll
        for (int u = 0; u < 8; ++u) acc8(a, r[u]);
#pragma unroll
        for (int u = 0; u < 8; ++u) r[u] = hb4[(size_t)s[8 + u] * 16 + q];
#pragma unroll
        for (int u = 0; u < 8; ++u) acc8(a, r[u]);
    }
    uint4 su = hb4[(size_t)i * 16 + q];     // self: weight 1 in scaled domain
    acc8(a, su);
    float dii = dis[i];
#pragma unroll
    for (int k = 0; k < 8; ++k) a[k] *= dii;
    if (BIAS) {
        float4 b0 = ((const float4*)bias)[2 * q];
        float4 b1 = ((const float4*)bias)[2 * q + 1];
        a[0] += b0.x; a[1] += b0.y; a[2] += b0.z; a[3] += b0.w;
        a[4] += b1.x; a[5] += b1.y; a[6] += b1.z; a[7] += b1.w;
    }
    if (RELU) {
#pragma unroll
        for (int k = 0; k < 8; ++k) a[k] = fmaxf(a[k], 0.f);
    }
    float sc = SCALEOUT ? dii : 1.f;
    ((uint4*)outb)[(size_t)i * 16 + q] =
        make_uint4(bf16pair(sc * a[0], sc * a[1]), bf16pair(sc * a[2], sc * a[3]),
                   bf16pair(sc * a[4], sc * a[5]), bf16pair(sc * a[6], sc * a[7]));
}

// K5c: layer-2 aggregate FUSED with mean-pool, group-per-node layout.
// 256 threads = 16 groups x 16 lanes; rows staged in LDS, then pool16-style
// flush (atomics amortized over 16 nodes).
__global__ __launch_bounds__(256) void aggregate_pool(const uint4* __restrict__ hb4,
                                                      const int* __restrict__ offsets,
                                                      const int* __restrict__ degs,
                                                      const unsigned short* __restrict__ csr,
                                                      const float* __restrict__ dis,
                                                      const int* __restrict__ batch,
                                                      float* __restrict__ g_acc,
                                                      float* __restrict__ g_cnt) {
    __shared__ float pool[16][128];   // [node][k*16+q] layout (<=4-way bank conflict)
    int tid = threadIdx.x;
    int grp = tid >> 4;               // 0..15: node within block
    int q   = tid & 15;               // uint4 column (features q*8 .. q*8+7)
    int i = blockIdx.x * 16 + grp;
    float a[8];
#pragma unroll
    for (int k = 0; k < 8; ++k) a[k] = 0.f;
    if (i < N_NODES) {
        int j = offsets[i];
        int e1 = j + ((degs[i] + 15) & ~15);
        for (; j < e1; j += 16) {
            int s[16];
            csr16(csr, j, s);
            uint4 r[8];
#pragma unroll
            for (int u = 0; u < 8; ++u) r[u] = hb4[(size_t)s[u] * 16 + q];
#pragma unroll
            for (int u = 0; u < 8; ++u) acc8(a, r[u]);
#pragma unroll
            for (int u = 0; u < 8; ++u) r[u] = hb4[(size_t)s[8 + u] * 16 + q];
#pragma unroll
            for (int u = 0; u < 8; ++u) acc8(a, r[u]);
        }
        uint4 su = hb4[(size_t)i * 16 + q];   // self: weight 1 in scaled domain
        acc8(a, su);
        float dii = dis[i];
#pragma unroll
        for (int k = 0; k < 8; ++k) a[k] *= dii;
    }
#pragma unroll
    for (int k = 0; k < 8; ++k) pool[grp][k * 16 + q] = a[k];
    __syncthreads();
    // flush phase: 128 threads accumulate the 16 rows, atomics per graph change
    if (tid < 128) {
        int f = tid;                              // feature index
        int lidx = (f & 7) * 16 + (f >> 3);       // LDS index for feature f
        int base = blockIdx.x * 16;
        float acc = 0.f; int cur = -1; float cnt = 0.f;
        for (int n = 0; n < 16; ++n) {
            int i2 = base + n;
            if (i2 >= N_NODES) break;
            int b = batch[i2];
            if (b != cur) {
                if (cur >= 0) {
                    atomicAdd(&g_acc[(size_t)cur * F_HID + f], acc);
                    if (f == 0) atomicAdd(&g_cnt[cur], cnt);
                }
                cur = b; acc = 0.f; cnt = 0.f;
            }
            acc += pool[n][lidx];
            cnt += 1.f;
        }
        if (cur >= 0) {
            atomicAdd(&g_acc[(size_t)cur * F_HID + f], acc);
            if (f == 0) atomicAdd(&g_cnt[cur], cnt);
        }
    }
}

// ---------------------------------------------------------------------------
// K7: fused graph head: g2 = (g_acc/cnt)@W2 + b2; g_hid = relu(g2@Wm1+bm1);
// out = g_hid@Wm2 + bm2.  One block per graph, 512 threads.
__global__ __launch_bounds__(512) void fused_mlp(const float* __restrict__ g_acc,
                                                 const float* __restrict__ g_cnt,
                                                 const float* __restrict__ W2,
                                                 const float* __restrict__ b2,
                                                 const float* __restrict__ Wm1,
                                                 const float* __restrict__ bm1,
                                                 const float* __restrict__ Wm2,
                                                 const float* __restrict__ bm2,
                                                 float* __restrict__ out) {
    __shared__ float pool_row[F_HID];
    __shared__ float g2row[F_HID];
    __shared__ float hid[N_HID];
    int g = blockIdx.x;
    int t = threadIdx.x;              // 0..511
    if (t < F_HID) {
        float c = g_cnt[g];
        pool_row[t] = g_acc[(size_t)g * F_HID + t] / fmaxf(c, 1.0f);
    }
    __syncthreads();
    if (t < F_HID) {
        float acc = b2[t];
        for (int k = 0; k < F_HID; ++k) acc += pool_row[k] * W2[(size_t)k * F_HID + t];
        g2row[t] = acc;
    }
    __syncthreads();
    {
        float acc = bm1[t];
        for (int k = 0; k < F_HID; ++k) acc += g2row[k] * Wm1[(size_t)k * N_HID + t];
        hid[t] = fmaxf(acc, 0.f);
    }
    __syncthreads();
    if (t < N_OUT) {
        float acc = bm2[t];
        for (int k = 0; k < N_HID; ++k) acc += hid[k] * Wm2[(size_t)k * N_OUT + t];
        out[(size_t)g * N_OUT + t] = acc;
    }
}

// ---------------------------------------------------------------------------
extern "C" void kernel_launch(void* const* d_in, const int* in_sizes, int n_in,
                              void* d_out, int out_size, void* d_ws, size_t ws_size,
                              hipStream_t stream) {
    const float* x   = (const float*)d_in[0];
    const int* ei    = (const int*)d_in[1];     // [2, E] int32
    const int* batch = (const int*)d_in[2];
    const float* W0 = (const float*)d_in[3];  const float* b0 = (const float*)d_in[4];
    const float* W1 = (const float*)d_in[5];  const float* b1 = (const float*)d_in[6];
    const float* W2 = (const float*)d_in[7];  const float* b2 = (const float*)d_in[8];
    const float* Wm1 = (const float*)d_in[9];  const float* bm1 = (const float*)d_in[10];
    const float* Wm2 = (const float*)d_in[11]; const float* bm2 = (const float*)d_in[12];

    // bump allocator on d_ws, 256B-aligned slots
    char* p = (char*)d_ws;
    auto alloc = [&](size_t bytes) -> char* {
        char* r = p;
        p += (bytes + 255) & ~(size_t)255;
        return r;
    };
    // zero-init region (contiguous in allocation order)
    int*   bucketCur = (int*)alloc(NBKT * 4);
    float* g_acc  = (float*)alloc((size_t)N_GRAPHS * F_HID * 4);
    float* g_cnt  = (float*)alloc(N_GRAPHS * 4);
    size_t zero_bytes = (size_t)(p - (char*)bucketCur);
    // rest
    unsigned int* binned = (unsigned int*)alloc((size_t)NBKT * BKT_S * 4);
    int*   offsets = (int*)alloc((size_t)N_NODES * 4);
    int*   degs    = (int*)alloc((size_t)N_NODES * 4);
    float* dis     = (float*)alloc((size_t)N_NODES * 4);
    unsigned short* csr = (unsigned short*)alloc((size_t)NBKT * BKT_CAP * 2 + 32);
    unsigned int* xb     = (unsigned int*)alloc((size_t)N_PAD * F_IN / 2 * 4);   // bf16 x' (dis-scaled) + zero row
    unsigned int* h_tmpb = (unsigned int*)alloc((size_t)N_PAD * F_HID / 2 * 4);  // bf16 (dis-scaled) + zero pad
    unsigned int* h_bb   = (unsigned int*)alloc((size_t)N_PAD * F_HID / 2 * 4);  // bf16 (dis-scaled) + zero row
    unsigned short* W0Tb = (unsigned short*)alloc((size_t)128 * F_IN * 2);
    unsigned short* W1Tb = (unsigned short*)alloc((size_t)128 * F_HID * 2);
    (void)ws_size; (void)in_sizes; (void)n_in; (void)out_size;

    (void)hipMemsetAsync(bucketCur, 0, zero_bytes, stream);

    // CSR construction: privatized binning -> per-bucket deg+scatter (fixed csrBase)
    bin_edges<<<NBIN_BLK, 256, 0, stream>>>(ei, bucketCur, binned);
    deg_scatter<<<NBKT, 256, 0, stream>>>(binned, bucketCur, degs, dis, offsets, csr);

    const int NCVT = N_NODES * F_IN / 4 + (F_IN + F_HID) * 128;
    cvt_all<<<(NCVT + 255) / 256, 256, 0, stream>>>(x, dis, xb, W0, W0Tb, W1, W1Tb);

    int mfma_grid = N_PAD / 64;                // 782 blocks
    int agg16_grid = N_NODES / 16 + 1;         // 3126: last block writes zero row
    int pool_grid = (N_NODES + 15) / 16;       // 3125

    // layers 0+1 front (fully fused): h_tmpb = bf16(dis * (relu((Â x')@W0+b0) @ W1))
    agg_gemm01<<<mfma_grid, 256, 0, stream>>>(
        (const uint4*)xb, x, offsets, degs, csr, dis,
        W0Tb, b0, W1Tb, h_tmpb, N_NODES);
    // layer 1 back: h_bb = bf16(dis * relu(Â h_tmp + b1))
    aggregate128g<true, true, true><<<agg16_grid, 256, 0, stream>>>(
        (const uint4*)h_tmpb, offsets, degs, csr, dis, b1, h_bb);
    // layer 2 (commuted) + pooling fused, group-per-node
    aggregate_pool<<<pool_grid, 256, 0, stream>>>(
        (const uint4*)h_bb, offsets, degs, csr, dis, batch, g_acc, g_cnt);

    // fused (W2 + MLP) head
    fused_mlp<<<N_GRAPHS, 512, 0, stream>>>(g_acc, g_cnt, W2, b2, Wm1, bm1, Wm2, bm2,
                                            (float*)d_out);
}

// Round 5
// 235.500 us; speedup vs baseline: 1.2706x; 1.0178x over previous
//
#include <hip/hip_runtime.h>
#include <hip/hip_bf16.h>
#include <math.h>
#include <stdint.h>

#define N_NODES 50000
#define N_PAD   50048   // padded rows for MFMA tile overrun (row 50000 = zero/dummy row)
#define N_EDGES 800000
#define N_GRAPHS 256
#define F_IN 64
#define F_HID 128
#define N_HID 512
#define N_OUT 256

#define NBKT   196           // buckets of 256 nodes (dst >> 8)
#define BKT_S  6144          // per-bucket binned capacity (expected 4082, +32 sigma)
#define BKT_CAP 8192         // fixed per-bucket CSR capacity (expected 5900, +18 sigma)
#define EPB    3328          // edges per bin_edges block (13 * 256)
#define NBIN_BLK ((N_EDGES + EPB - 1) / EPB)   // 241
#define DUMMY_NODE N_NODES   // zero row index for CSR pad slots

using bf16x8 = __attribute__((ext_vector_type(8))) short;   // MFMA A/B frag (4 VGPRs)
using f32x4  = __attribute__((ext_vector_type(4))) float;   // MFMA C/D frag

// pack two fp32 into a uint holding two bf16 (RNE); low16 = a, high16 = b
__device__ __forceinline__ unsigned int bf16pair(float a, float b) {
    unsigned int ua = __float_as_uint(a);
    unsigned int ub = __float_as_uint(b);
    ua += 0x7fffu + ((ua >> 16) & 1u);
    ub += 0x7fffu + ((ub >> 16) & 1u);
    return (ua >> 16) | (ub & 0xffff0000u);
}
__device__ __forceinline__ unsigned short bf16one(float a) {
    unsigned int ua = __float_as_uint(a);
    ua += 0x7fffu + ((ua >> 16) & 1u);
    return (unsigned short)(ua >> 16);
}
__device__ __forceinline__ float bf16lo(unsigned int u) { return __uint_as_float(u << 16); }
__device__ __forceinline__ float bf16hi(unsigned int u) { return __uint_as_float(u & 0xffff0000u); }

// accumulate 8 bf16 features from a uint4 into a[0..7]
__device__ __forceinline__ void acc8(float* a, uint4 r) {
    a[0] += bf16lo(r.x);  a[1] += bf16hi(r.x);
    a[2] += bf16lo(r.y);  a[3] += bf16hi(r.y);
    a[4] += bf16lo(r.z);  a[5] += bf16hi(r.z);
    a[6] += bf16lo(r.w);  a[7] += bf16hi(r.w);
}

// unpack 16 csr entries (uniform within a lane group; cached/broadcast loads)
__device__ __forceinline__ void csr16(const unsigned short* __restrict__ csr, int j, int* s) {
    uint4 w0 = *(const uint4*)&csr[j];
    uint4 w1 = *(const uint4*)&csr[j + 8];
    s[0] = w0.x & 0xffff;  s[1] = w0.x >> 16;
    s[2] = w0.y & 0xffff;  s[3] = w0.y >> 16;
    s[4] = w0.z & 0xffff;  s[5] = w0.z >> 16;
    s[6] = w0.w & 0xffff;  s[7] = w0.w >> 16;
    s[8] = w1.x & 0xffff;  s[9] = w1.x >> 16;
    s[10] = w1.y & 0xffff; s[11] = w1.y >> 16;
    s[12] = w1.z & 0xffff; s[13] = w1.z >> 16;
    s[14] = w1.w & 0xffff; s[15] = w1.w >> 16;
}

// ---------------------------------------------------------------------------
// K0 (merged): xb'[s] = bf16(dis[s] * x[s]) + zero pad row; both weight tables
// fp32 [K][128] -> bf16 [128][K] in the same dispatch.
__global__ void cvt_all(const float* __restrict__ in, const float* __restrict__ dis,
                        unsigned int* __restrict__ xb,
                        const float* __restrict__ W0, unsigned short* __restrict__ W0Tb,
                        const float* __restrict__ W1, unsigned short* __restrict__ W1Tb) {
    const int NX = N_NODES * F_IN / 4;          // 800000 float4 slots
    int idx = blockIdx.x * blockDim.x + threadIdx.x;
    if (idx < NX) {
        int node = idx >> 4;                    // 16 float4 per 64-f row
        float d = dis[node];
        float4 v = ((const float4*)in)[idx];
        ((uint2*)xb)[idx] = make_uint2(bf16pair(d * v.x, d * v.y),
                                       bf16pair(d * v.z, d * v.w));
        if (idx < 16)                            // zero dummy row 50000
            ((uint2*)xb)[(size_t)N_NODES * 16 + idx] = make_uint2(0u, 0u);
    } else {
        int j = idx - NX;
        const int N0 = F_IN * 128;
        const int N1 = F_HID * 128;
        if (j < N0) {
            int k = j >> 7, n = j & 127;
            W0Tb[n * F_IN + k] = bf16one(W0[j]);
        } else if (j < N0 + N1) {
            int jj = j - N0;
            int k = jj >> 7, n = jj & 127;
            W1Tb[n * F_HID + k] = bf16one(W1[jj]);
        }
    }
}

// ---------------------------------------------------------------------------
// K1: bin edges by dst>>8 through LDS staging (privatized binning).
__global__ __launch_bounds__(256) void bin_edges(const int* __restrict__ ei,
                                                 int* __restrict__ bucketCur,
                                                 unsigned int* __restrict__ binned) {
    __shared__ int hist[NBKT];
    __shared__ int lbase[NBKT];
    __shared__ int lcur[NBKT];
    __shared__ int gbase[NBKT];
    __shared__ int scn[256];
    __shared__ unsigned int staging[EPB];
    int tid = threadIdx.x;
    int base = blockIdx.x * EPB;
    int cnt = N_EDGES - base; if (cnt > EPB) cnt = EPB;
    if (tid < NBKT) hist[tid] = 0;
    __syncthreads();
    unsigned int pk[13]; int nk = 0;
#pragma unroll
    for (int u = 0; u < 13; ++u) {
        int e = base + u * 256 + tid;
        if (u * 256 + tid < cnt) {
            unsigned int s = (unsigned int)ei[e];
            unsigned int d = (unsigned int)ei[N_EDGES + e];
            unsigned int b = d >> 8;
            pk[nk++] = (b << 24) | (s << 8) | (d & 255u);
        }
    }
    for (int u = 0; u < nk; ++u) atomicAdd(&hist[pk[u] >> 24], 1);
    __syncthreads();
    // parallel exclusive scan over the 196 bucket counts
    int h = (tid < NBKT) ? hist[tid] : 0;
    scn[tid] = h;
    __syncthreads();
    for (int off = 1; off < 256; off <<= 1) {
        int t = (tid >= off) ? scn[tid - off] : 0;
        __syncthreads();
        scn[tid] += t;
        __syncthreads();
    }
    if (tid < NBKT) { int e0 = scn[tid] - h; lbase[tid] = e0; lcur[tid] = e0; }
    __syncthreads();
    for (int u = 0; u < nk; ++u) {
        int pos = atomicAdd(&lcur[pk[u] >> 24], 1);
        staging[pos] = pk[u];
    }
    if (tid < NBKT && hist[tid] > 0)
        gbase[tid] = atomicAdd(&bucketCur[tid], hist[tid]);
    __syncthreads();
    for (int k = tid; k < cnt; k += 256) {
        unsigned int v = staging[k];
        int b = v >> 24;
        binned[(size_t)b * BKT_S + gbase[b] + (k - lbase[b])] = v & 0xffffffu;
    }
}

// K2 (merged deg + scatter): histogram -> degs/dis/offsets (csrBase fixed at
// b*BKT_CAP: no inter-bucket scan), CSR built in LDS, streamed out coalesced.
__global__ __launch_bounds__(256) void deg_scatter(const unsigned int* __restrict__ binned,
                                                   const int* __restrict__ bucketCur,
                                                   int* __restrict__ degs,
                                                   float* __restrict__ dis,
                                                   int* __restrict__ offsets,
                                                   unsigned short* __restrict__ csr) {
    __shared__ int hist[256];
    __shared__ int tsum[256];
    __shared__ int lcur[256];
    __shared__ uint4 scsr4[BKT_CAP / 8];   // 16 KB CSR staging
    unsigned short* scsr = (unsigned short*)scsr4;
    int b = blockIdx.x;
    int tid = threadIdx.x;
    int node0 = b << 8;
    hist[tid] = 0;
    __syncthreads();
    int cnt = bucketCur[b];
    const unsigned int* bb = &binned[(size_t)b * BKT_S];
    for (int k = tid; k < cnt; k += 256)
        atomicAdd(&hist[bb[k] & 255u], 1);
    __syncthreads();
    int d = hist[tid];
    int s = (d + 15) & ~15;          // align-16 so aggregates run full 16-edge chunks
    tsum[tid] = s;
    __syncthreads();
    for (int off = 1; off < 256; off <<= 1) {
        int t = (tid >= off) ? tsum[tid - off] : 0;
        __syncthreads();
        tsum[tid] += t;
        __syncthreads();
    }
    int excl = tsum[tid] - s;
    int tot = tsum[255];              // multiple of 16
    int csrB = b * BKT_CAP;
    int node = node0 + tid;
    if (node < N_NODES) {
        degs[node] = d;
        dis[node] = rsqrtf((float)(d + 1));
        offsets[node] = csrB + excl;
    }
    lcur[tid] = excl;
    // dummy-fill the aligned LDS region (uint2 = 4 entries; tot % 16 == 0)
    uint2 dv = make_uint2(0xC350C350u, 0xC350C350u);   // 50000 | 50000<<16
    for (int k = tid; k < (tot >> 2); k += 256) ((uint2*)scsr)[k] = dv;
    __syncthreads();
    for (int k = tid; k < cnt; k += 256) {
        unsigned int v = bb[k];
        int dl = v & 255u;
        int p = atomicAdd(&lcur[dl], 1);
        scsr[p] = (unsigned short)(v >> 8);
    }
    __syncthreads();
    for (int k = tid; k < (tot >> 3); k += 256)
        ((uint4*)(csr + csrB))[k] = scsr4[k];
}

// ---------------------------------------------------------------------------
// K4 v3 (fused L0-aggregate + W0 GEMM + W1 GEMM), 512 threads:
//   phase A: 64 groups x 8 lanes -- ALL 64 nodes gathered in parallel (one
//            pass) into the XOR-swizzled LDS A-tile.
//   phase B: 8 waves, column-split GEMM. Wave (half=wv>>2, wq=wv&3) computes
//            rows 16*wq..16*wq+15 x cols 64*half..64*half+63 (acc[4]).
//            C0 tile written by both halves (disjoint), then K=128 GEMM.
__global__ __launch_bounds__(512) void agg_gemm01(const uint4* __restrict__ xb4,
                                                  const float* __restrict__ x,
                                                  const int* __restrict__ offsets,
                                                  const int* __restrict__ degs,
                                                  const unsigned short* __restrict__ csr,
                                                  const float* __restrict__ dis,
                                                  const unsigned short* __restrict__ W0T,
                                                  const float* __restrict__ b0,
                                                  const unsigned short* __restrict__ W1T,
                                                  unsigned int* __restrict__ outb, int M) {
    __shared__ unsigned short atile[64 * 64];      // 8 KB A tile (XOR swizzled rows)
    __shared__ unsigned short tile[4][16 * 128];   // 16 KB C0 tiles (per 16-row band)
    int tid = threadIdx.x;
    int row0 = blockIdx.x * 64;
    char* at = (char*)atile;
    // ---- phase A: aggregate 64 nodes in parallel ----
    {
        int grp = tid >> 3;              // 0..63: node within tile
        int q   = tid & 7;               // uint4 col (features q*8..q*8+7)
        int i = row0 + grp;
        float a[8];
#pragma unroll
        for (int k = 0; k < 8; ++k) a[k] = 0.f;
        if (i < N_NODES) {
            int j = offsets[i];
            int e1 = j + ((degs[i] + 15) & ~15);
            for (; j < e1; j += 16) {
                int s[16];
                csr16(csr, j, s);
                uint4 r[8];
#pragma unroll
                for (int u = 0; u < 8; ++u) r[u] = xb4[(size_t)s[u] * 8 + q];
#pragma unroll
                for (int u = 0; u < 8; ++u) acc8(a, r[u]);
#pragma unroll
                for (int u = 0; u < 8; ++u) r[u] = xb4[(size_t)s[8 + u] * 8 + q];
#pragma unroll
                for (int u = 0; u < 8; ++u) acc8(a, r[u]);
            }
            float dii = dis[i];
            float d2 = dii * dii;
            float4 sx0 = ((const float4*)x)[(size_t)i * 16 + 2 * q];   // self fp32
            float4 sx1 = ((const float4*)x)[(size_t)i * 16 + 2 * q + 1];
            a[0] = dii * a[0] + d2 * sx0.x;  a[1] = dii * a[1] + d2 * sx0.y;
            a[2] = dii * a[2] + d2 * sx0.z;  a[3] = dii * a[3] + d2 * sx0.w;
            a[4] = dii * a[4] + d2 * sx1.x;  a[5] = dii * a[5] + d2 * sx1.y;
            a[6] = dii * a[6] + d2 * sx1.z;  a[7] = dii * a[7] + d2 * sx1.w;
        }
        int byte = (grp * 128 + q * 16) ^ ((grp & 7) << 4);
        *(uint4*)(at + byte) =
            make_uint4(bf16pair(a[0], a[1]), bf16pair(a[2], a[3]),
                       bf16pair(a[4], a[5]), bf16pair(a[6], a[7]));
    }
    __syncthreads();
    // ---- phase B: dual GEMM, 8 waves column-split ----
    int wv = tid >> 6;                 // 0..7
    int half = wv >> 2;                // 0..1: which 64-col half
    int wq = wv & 3;                   // 0..3: which 16-row band
    int lane = tid & 63;
    int m = lane & 15;
    int quad = lane >> 4;
    int wrow0 = row0 + wq * 16;
    char* tl = (char*)&tile[wq][0];
    f32x4 acc[4];
#pragma unroll
    for (int t = 0; t < 4; ++t) acc[t] = (f32x4){0.f, 0.f, 0.f, 0.f};
    // phase 1: K = 64 (A @ W0), A-frags from swizzled LDS A-tile
#pragma unroll
    for (int ks = 0; ks < F_IN; ks += 32) {
        int abyte = ((wq * 16 + m) * 128 + (ks + quad * 8) * 2) ^ ((m & 7) << 4);
        bf16x8 af = *(const bf16x8*)(at + abyte);
#pragma unroll
        for (int t = 0; t < 4; ++t) {
            int col = half * 64 + t * 16 + m;
            bf16x8 bf = *(const bf16x8*)&W0T[(size_t)col * F_IN + ks + quad * 8];
            acc[t] = __builtin_amdgcn_mfma_f32_16x16x32_bf16(af, bf, acc[t], 0, 0, 0);
        }
    }
    // epilogue 1: bias + relu -> bf16 -> swizzled LDS (row = quad*4+r local)
#pragma unroll
    for (int t = 0; t < 4; ++t) {
        int col = half * 64 + t * 16 + m;
        float bcol = b0[col];
#pragma unroll
        for (int r = 0; r < 4; ++r) {
            int row = quad * 4 + r;
            float v = fmaxf(acc[t][r] + bcol, 0.f);
            int byte = (row * 256 + col * 2) ^ ((row & 7) << 4);
            *(unsigned short*)(tl + byte) = bf16one(v);
        }
    }
    __syncthreads();
    // phase 2: K = 128 (C0 @ W1), A-frags from swizzled LDS
#pragma unroll
    for (int t = 0; t < 4; ++t) acc[t] = (f32x4){0.f, 0.f, 0.f, 0.f};
#pragma unroll
    for (int ks = 0; ks < F_HID; ks += 32) {
        int byte = (m * 256 + ks * 2 + quad * 16) ^ ((m & 7) << 4);
        bf16x8 af = *(const bf16x8*)(tl + byte);
#pragma unroll
        for (int t = 0; t < 4; ++t) {
            int col = half * 64 + t * 16 + m;
            bf16x8 bf = *(const bf16x8*)&W1T[(size_t)col * F_HID + ks + quad * 8];
            acc[t] = __builtin_amdgcn_mfma_f32_16x16x32_bf16(af, bf, acc[t], 0, 0, 0);
        }
    }
    // epilogue 2: dis-scale, pair-write bf16, zero pad rows
    float dr[4];
#pragma unroll
    for (int r = 0; r < 4; ++r) {
        int row = wrow0 + quad * 4 + r;
        dr[r] = (row < M) ? dis[row] : 0.f;
    }
#pragma unroll
    for (int t = 0; t < 4; ++t) {
        int col = half * 64 + t * 16 + m;
#pragma unroll
        for (int r = 0; r < 4; ++r) {
            float v = acc[t][r] * dr[r];
            float vn = __shfl_xor(v, 1, 64);    // neighbor col's value
            if ((m & 1) == 0) {
                int row = wrow0 + quad * 4 + r;
                outb[(size_t)row * 64 + (col >> 1)] = (row < M) ? bf16pair(v, vn) : 0u;
            }
        }
    }
}

// ---------------------------------------------------------------------------
// K5a v2: F=128 aggregate, group-per-node (16 groups x 16 lanes). Lane q owns
// uint4 column q end-to-end: 16 independent gathers in flight per chunk, no
// cross-lane shuffles, coalesced 256 B per row, direct uint4 store.
template <bool RELU, bool BIAS, bool SCALEOUT>
__global__ __launch_bounds__(256) void aggregate128g(const uint4* __restrict__ hb4,
                                                     const int* __restrict__ offsets,
                                                     const int* __restrict__ degs,
                                                     const unsigned short* __restrict__ csr,
                                                     const float* __restrict__ dis,
                                                     const float* __restrict__ bias,
                                                     unsigned int* __restrict__ outb) {
    int tid = threadIdx.x;
    int grp = tid >> 4;               // 0..15: node within block
    int q   = tid & 15;               // uint4 column (features q*8..q*8+7)
    int i = blockIdx.x * 16 + grp;
    if (i >= N_NODES) {
        if (i == N_NODES)             // zero dummy row for downstream gathers
            ((uint4*)outb)[(size_t)N_NODES * 16 + q] = make_uint4(0u, 0u, 0u, 0u);
        return;
    }
    float a[8];
#pragma unroll
    for (int k = 0; k < 8; ++k) a[k] = 0.f;
    int j = offsets[i];
    int e1 = j + ((degs[i] + 15) & ~15);
    for (; j < e1; j += 16) {
        int s[16];
        csr16(csr, j, s);
        uint4 r[8];
#pragma unroll
        for (int u = 0; u < 8; ++u) r[u] = hb4[(size_t)s[u] * 16 + q];
#pragma unroll
        for (int u = 0; u < 8; ++u) acc8(a, r[u]);
#pragma unroll
        for (int u = 0; u < 8; ++u) r[u] = hb4[(size_t)s[8 + u] * 16 + q];
#pragma unroll
        for (int u = 0; u < 8; ++u) acc8(a, r[u]);
    }
    uint4 su = hb4[(size_t)i * 16 + q];     // self: weight 1 in scaled domain
    acc8(a, su);
    float dii = dis[i];
#pragma unroll
    for (int k = 0; k < 8; ++k) a[k] *= dii;
    if (BIAS) {
        float4 b0 = ((const float4*)bias)[2 * q];
        float4 b1 = ((const float4*)bias)[2 * q + 1];
        a[0] += b0.x; a[1] += b0.y; a[2] += b0.z; a[3] += b0.w;
        a[4] += b1.x; a[5] += b1.y; a[6] += b1.z; a[7] += b1.w;
    }
    if (RELU) {
#pragma unroll
        for (int k = 0; k < 8; ++k) a[k] = fmaxf(a[k], 0.f);
    }
    float sc = SCALEOUT ? dii : 1.f;
    ((uint4*)outb)[(size_t)i * 16 + q] =
        make_uint4(bf16pair(sc * a[0], sc * a[1]), bf16pair(sc * a[2], sc * a[3]),
                   bf16pair(sc * a[4], sc * a[5]), bf16pair(sc * a[6], sc * a[7]));
}

// K5c: layer-2 aggregate FUSED with mean-pool, group-per-node layout.
// 256 threads = 16 groups x 16 lanes; rows staged in LDS, then pool16-style
// flush (atomics amortized over 16 nodes).
__global__ __launch_bounds__(256) void aggregate_pool(const uint4* __restrict__ hb4,
                                                      const int* __restrict__ offsets,
                                                      const int* __restrict__ degs,
                                                      const unsigned short* __restrict__ csr,
                                                      const float* __restrict__ dis,
                                                      const int* __restrict__ batch,
                                                      float* __restrict__ g_acc,
                                                      float* __restrict__ g_cnt) {
    __shared__ float pool[16][128];   // [node][k*16+q] layout (<=4-way bank conflict)
    int tid = threadIdx.x;
    int grp = tid >> 4;               // 0..15: node within block
    int q   = tid & 15;               // uint4 column (features q*8 .. q*8+7)
    int i = blockIdx.x * 16 + grp;
    float a[8];
#pragma unroll
    for (int k = 0; k < 8; ++k) a[k] = 0.f;
    if (i < N_NODES) {
        int j = offsets[i];
        int e1 = j + ((degs[i] + 15) & ~15);
        for (; j < e1; j += 16) {
            int s[16];
            csr16(csr, j, s);
            uint4 r[8];
#pragma unroll
            for (int u = 0; u < 8; ++u) r[u] = hb4[(size_t)s[u] * 16 + q];
#pragma unroll
            for (int u = 0; u < 8; ++u) acc8(a, r[u]);
#pragma unroll
            for (int u = 0; u < 8; ++u) r[u] = hb4[(size_t)s[8 + u] * 16 + q];
#pragma unroll
            for (int u = 0; u < 8; ++u) acc8(a, r[u]);
        }
        uint4 su = hb4[(size_t)i * 16 + q];   // self: weight 1 in scaled domain
        acc8(a, su);
        float dii = dis[i];
#pragma unroll
        for (int k = 0; k < 8; ++k) a[k] *= dii;
    }
#pragma unroll
    for (int k = 0; k < 8; ++k) pool[grp][k * 16 + q] = a[k];
    __syncthreads();
    // flush phase: 128 threads accumulate the 16 rows, atomics per graph change
    if (tid < 128) {
        int f = tid;                              // feature index
        int lidx = (f & 7) * 16 + (f >> 3);       // LDS index for feature f
        int base = blockIdx.x * 16;
        float acc = 0.f; int cur = -1; float cnt = 0.f;
        for (int n = 0; n < 16; ++n) {
            int i2 = base + n;
            if (i2 >= N_NODES) break;
            int b = batch[i2];
            if (b != cur) {
                if (cur >= 0) {
                    atomicAdd(&g_acc[(size_t)cur * F_HID + f], acc);
                    if (f == 0) atomicAdd(&g_cnt[cur], cnt);
                }
                cur = b; acc = 0.f; cnt = 0.f;
            }
            acc += pool[n][lidx];
            cnt += 1.f;
        }
        if (cur >= 0) {
            atomicAdd(&g_acc[(size_t)cur * F_HID + f], acc);
            if (f == 0) atomicAdd(&g_cnt[cur], cnt);
        }
    }
}

// ---------------------------------------------------------------------------
// K7: fused graph head: g2 = (g_acc/cnt)@W2 + b2; g_hid = relu(g2@Wm1+bm1);
// out = g_hid@Wm2 + bm2.  One block per graph, 512 threads.
__global__ __launch_bounds__(512) void fused_mlp(const float* __restrict__ g_acc,
                                                 const float* __restrict__ g_cnt,
                                                 const float* __restrict__ W2,
                                                 const float* __restrict__ b2,
                                                 const float* __restrict__ Wm1,
                                                 const float* __restrict__ bm1,
                                                 const float* __restrict__ Wm2,
                                                 const float* __restrict__ bm2,
                                                 float* __restrict__ out) {
    __shared__ float pool_row[F_HID];
    __shared__ float g2row[F_HID];
    __shared__ float hid[N_HID];
    int g = blockIdx.x;
    int t = threadIdx.x;              // 0..511
    if (t < F_HID) {
        float c = g_cnt[g];
        pool_row[t] = g_acc[(size_t)g * F_HID + t] / fmaxf(c, 1.0f);
    }
    __syncthreads();
    if (t < F_HID) {
        float acc = b2[t];
        for (int k = 0; k < F_HID; ++k) acc += pool_row[k] * W2[(size_t)k * F_HID + t];
        g2row[t] = acc;
    }
    __syncthreads();
    {
        float acc = bm1[t];
        for (int k = 0; k < F_HID; ++k) acc += g2row[k] * Wm1[(size_t)k * N_HID + t];
        hid[t] = fmaxf(acc, 0.f);
    }
    __syncthreads();
    if (t < N_OUT) {
        float acc = bm2[t];
        for (int k = 0; k < N_HID; ++k) acc += hid[k] * Wm2[(size_t)k * N_OUT + t];
        out[(size_t)g * N_OUT + t] = acc;
    }
}

// ---------------------------------------------------------------------------
extern "C" void kernel_launch(void* const* d_in, const int* in_sizes, int n_in,
                              void* d_out, int out_size, void* d_ws, size_t ws_size,
                              hipStream_t stream) {
    const float* x   = (const float*)d_in[0];
    const int* ei    = (const int*)d_in[1];     // [2, E] int32
    const int* batch = (const int*)d_in[2];
    const float* W0 = (const float*)d_in[3];  const float* b0 = (const float*)d_in[4];
    const float* W1 = (const float*)d_in[5];  const float* b1 = (const float*)d_in[6];
    const float* W2 = (const float*)d_in[7];  const float* b2 = (const float*)d_in[8];
    const float* Wm1 = (const float*)d_in[9];  const float* bm1 = (const float*)d_in[10];
    const float* Wm2 = (const float*)d_in[11]; const float* bm2 = (const float*)d_in[12];

    // bump allocator on d_ws, 256B-aligned slots
    char* p = (char*)d_ws;
    auto alloc = [&](size_t bytes) -> char* {
        char* r = p;
        p += (bytes + 255) & ~(size_t)255;
        return r;
    };
    // zero-init region (contiguous in allocation order)
    int*   bucketCur = (int*)alloc(NBKT * 4);
    float* g_acc  = (float*)alloc((size_t)N_GRAPHS * F_HID * 4);
    float* g_cnt  = (float*)alloc(N_GRAPHS * 4);
    size_t zero_bytes = (size_t)(p - (char*)bucketCur);
    // rest
    unsigned int* binned = (unsigned int*)alloc((size_t)NBKT * BKT_S * 4);
    int*   offsets = (int*)alloc((size_t)N_NODES * 4);
    int*   degs    = (int*)alloc((size_t)N_NODES * 4);
    float* dis     = (float*)alloc((size_t)N_NODES * 4);
    unsigned short* csr = (unsigned short*)alloc((size_t)NBKT * BKT_CAP * 2 + 32);
    unsigned int* xb     = (unsigned int*)alloc((size_t)N_PAD * F_IN / 2 * 4);   // bf16 x' (dis-scaled) + zero row
    unsigned int* h_tmpb = (unsigned int*)alloc((size_t)N_PAD * F_HID / 2 * 4);  // bf16 (dis-scaled) + zero pad
    unsigned int* h_bb   = (unsigned int*)alloc((size_t)N_PAD * F_HID / 2 * 4);  // bf16 (dis-scaled) + zero row
    unsigned short* W0Tb = (unsigned short*)alloc((size_t)128 * F_IN * 2);
    unsigned short* W1Tb = (unsigned short*)alloc((size_t)128 * F_HID * 2);
    (void)ws_size; (void)in_sizes; (void)n_in; (void)out_size;

    (void)hipMemsetAsync(bucketCur, 0, zero_bytes, stream);

    // CSR construction: privatized binning -> per-bucket deg+scatter (fixed csrBase)
    bin_edges<<<NBIN_BLK, 256, 0, stream>>>(ei, bucketCur, binned);
    deg_scatter<<<NBKT, 256, 0, stream>>>(binned, bucketCur, degs, dis, offsets, csr);

    const int NCVT = N_NODES * F_IN / 4 + (F_IN + F_HID) * 128;
    cvt_all<<<(NCVT + 255) / 256, 256, 0, stream>>>(x, dis, xb, W0, W0Tb, W1, W1Tb);

    int mfma_grid = N_PAD / 64;                // 782 blocks
    int agg16_grid = N_NODES / 16 + 1;         // 3126: last block writes zero row
    int pool_grid = (N_NODES + 15) / 16;       // 3125

    // layers 0+1 front (fully fused): h_tmpb = bf16(dis * (relu((Â x')@W0+b0) @ W1))
    agg_gemm01<<<mfma_grid, 512, 0, stream>>>(
        (const uint4*)xb, x, offsets, degs, csr, dis,
        W0Tb, b0, W1Tb, h_tmpb, N_NODES);
    // layer 1 back: h_bb = bf16(dis * relu(Â h_tmp + b1))
    aggregate128g<true, true, true><<<agg16_grid, 256, 0, stream>>>(
        (const uint4*)h_tmpb, offsets, degs, csr, dis, b1, h_bb);
    // layer 2 (commuted) + pooling fused, group-per-node
    aggregate_pool<<<pool_grid, 256, 0, stream>>>(
        (const uint4*)h_bb, offsets, degs, csr, dis, batch, g_acc, g_cnt);

    // fused (W2 + MLP) head
    fused_mlp<<<N_GRAPHS, 512, 0, stream>>>(g_acc, g_cnt, W2, b2, Wm1, bm1, Wm2, bm2,
                                            (float*)d_out);
}

// Round 6
// 235.304 us; speedup vs baseline: 1.2716x; 1.0008x over previous
//
#include <hip/hip_runtime.h>
#include <hip/hip_bf16.h>
#include <math.h>
#include <stdint.h>

#define N_NODES 50000
#define N_PAD   50048   // padded rows for MFMA tile overrun (row 50000 = zero/dummy row)
#define N_EDGES 800000
#define N_GRAPHS 256
#define F_IN 64
#define F_HID 128
#define N_HID 512
#define N_OUT 256

#define NBKT   196           // buckets of 256 nodes (dst >> 8)
#define BKT_S  6144          // per-bucket binned capacity (expected 4082, +32 sigma)
#define BKT_CAP 8192         // fixed per-bucket CSR capacity (expected 5900, +18 sigma)
#define EPB    3328          // edges per bin_edges block (13 * 256)
#define NBIN_BLK ((N_EDGES + EPB - 1) / EPB)   // 241
#define DUMMY_NODE N_NODES   // zero row index for CSR pad slots

using bf16x8 = __attribute__((ext_vector_type(8))) short;   // MFMA A/B frag (4 VGPRs)
using f32x4  = __attribute__((ext_vector_type(4))) float;   // MFMA C/D frag

// pack two fp32 into a uint holding two bf16 (RNE); low16 = a, high16 = b
__device__ __forceinline__ unsigned int bf16pair(float a, float b) {
    unsigned int ua = __float_as_uint(a);
    unsigned int ub = __float_as_uint(b);
    ua += 0x7fffu + ((ua >> 16) & 1u);
    ub += 0x7fffu + ((ub >> 16) & 1u);
    return (ua >> 16) | (ub & 0xffff0000u);
}
__device__ __forceinline__ unsigned short bf16one(float a) {
    unsigned int ua = __float_as_uint(a);
    ua += 0x7fffu + ((ua >> 16) & 1u);
    return (unsigned short)(ua >> 16);
}
__device__ __forceinline__ float bf16lo(unsigned int u) { return __uint_as_float(u << 16); }
__device__ __forceinline__ float bf16hi(unsigned int u) { return __uint_as_float(u & 0xffff0000u); }

// accumulate 8 bf16 features from a uint4 into a[0..7]
__device__ __forceinline__ void acc8(float* a, uint4 r) {
    a[0] += bf16lo(r.x);  a[1] += bf16hi(r.x);
    a[2] += bf16lo(r.y);  a[3] += bf16hi(r.y);
    a[4] += bf16lo(r.z);  a[5] += bf16hi(r.z);
    a[6] += bf16lo(r.w);  a[7] += bf16hi(r.w);
}

// unpack 16 csr entries (uniform within a lane group; cached/broadcast loads)
__device__ __forceinline__ void csr16(const unsigned short* __restrict__ csr, int j, int* s) {
    uint4 w0 = *(const uint4*)&csr[j];
    uint4 w1 = *(const uint4*)&csr[j + 8];
    s[0] = w0.x & 0xffff;  s[1] = w0.x >> 16;
    s[2] = w0.y & 0xffff;  s[3] = w0.y >> 16;
    s[4] = w0.z & 0xffff;  s[5] = w0.z >> 16;
    s[6] = w0.w & 0xffff;  s[7] = w0.w >> 16;
    s[8] = w1.x & 0xffff;  s[9] = w1.x >> 16;
    s[10] = w1.y & 0xffff; s[11] = w1.y >> 16;
    s[12] = w1.z & 0xffff; s[13] = w1.z >> 16;
    s[14] = w1.w & 0xffff; s[15] = w1.w >> 16;
}

// ---------------------------------------------------------------------------
// K0 (merged): xb'[s] = bf16(dis[s] * x[s]) + zero pad row; both weight tables
// fp32 [K][128] -> bf16 [128][K] in the same dispatch.
__global__ void cvt_all(const float* __restrict__ in, const float* __restrict__ dis,
                        unsigned int* __restrict__ xb,
                        const float* __restrict__ W0, unsigned short* __restrict__ W0Tb,
                        const float* __restrict__ W1, unsigned short* __restrict__ W1Tb) {
    const int NX = N_NODES * F_IN / 4;          // 800000 float4 slots
    int idx = blockIdx.x * blockDim.x + threadIdx.x;
    if (idx < NX) {
        int node = idx >> 4;                    // 16 float4 per 64-f row
        float d = dis[node];
        float4 v = ((const float4*)in)[idx];
        ((uint2*)xb)[idx] = make_uint2(bf16pair(d * v.x, d * v.y),
                                       bf16pair(d * v.z, d * v.w));
        if (idx < 16)                            // zero dummy row 50000
            ((uint2*)xb)[(size_t)N_NODES * 16 + idx] = make_uint2(0u, 0u);
    } else {
        int j = idx - NX;
        const int N0 = F_IN * 128;
        const int N1 = F_HID * 128;
        if (j < N0) {
            int k = j >> 7, n = j & 127;
            W0Tb[n * F_IN + k] = bf16one(W0[j]);
        } else if (j < N0 + N1) {
            int jj = j - N0;
            int k = jj >> 7, n = jj & 127;
            W1Tb[n * F_HID + k] = bf16one(W1[jj]);
        }
    }
}

// ---------------------------------------------------------------------------
// K1: bin edges by dst>>8 through LDS staging (privatized binning).
__global__ __launch_bounds__(256) void bin_edges(const int* __restrict__ ei,
                                                 int* __restrict__ bucketCur,
                                                 unsigned int* __restrict__ binned) {
    __shared__ int hist[NBKT];
    __shared__ int lbase[NBKT];
    __shared__ int lcur[NBKT];
    __shared__ int gbase[NBKT];
    __shared__ int scn[256];
    __shared__ unsigned int staging[EPB];
    int tid = threadIdx.x;
    int base = blockIdx.x * EPB;
    int cnt = N_EDGES - base; if (cnt > EPB) cnt = EPB;
    if (tid < NBKT) hist[tid] = 0;
    __syncthreads();
    unsigned int pk[13]; int nk = 0;
#pragma unroll
    for (int u = 0; u < 13; ++u) {
        int e = base + u * 256 + tid;
        if (u * 256 + tid < cnt) {
            unsigned int s = (unsigned int)ei[e];
            unsigned int d = (unsigned int)ei[N_EDGES + e];
            unsigned int b = d >> 8;
            pk[nk++] = (b << 24) | (s << 8) | (d & 255u);
        }
    }
    for (int u = 0; u < nk; ++u) atomicAdd(&hist[pk[u] >> 24], 1);
    __syncthreads();
    // parallel exclusive scan over the 196 bucket counts
    int h = (tid < NBKT) ? hist[tid] : 0;
    scn[tid] = h;
    __syncthreads();
    for (int off = 1; off < 256; off <<= 1) {
        int t = (tid >= off) ? scn[tid - off] : 0;
        __syncthreads();
        scn[tid] += t;
        __syncthreads();
    }
    if (tid < NBKT) { int e0 = scn[tid] - h; lbase[tid] = e0; lcur[tid] = e0; }
    __syncthreads();
    for (int u = 0; u < nk; ++u) {
        int pos = atomicAdd(&lcur[pk[u] >> 24], 1);
        staging[pos] = pk[u];
    }
    if (tid < NBKT && hist[tid] > 0)
        gbase[tid] = atomicAdd(&bucketCur[tid], hist[tid]);
    __syncthreads();
    for (int k = tid; k < cnt; k += 256) {
        unsigned int v = staging[k];
        int b = v >> 24;
        binned[(size_t)b * BKT_S + gbase[b] + (k - lbase[b])] = v & 0xffffffu;
    }
}

// K2 (merged deg + scatter, OCTANT-GROUPED): per-(node, src-octant) histogram
// -> each node's edge list is grouped by src>>13. All gather kernels then walk
// octant 0 slices first, then octant 1, ... -> the hot read window at any
// instant is ~1-2 slices (0.8-2 MB per table) -> per-XCD-L2 resident.
// csrBase fixed at b*BKT_CAP; CSR built in LDS, streamed out coalesced.
__global__ __launch_bounds__(256) void deg_scatter(const unsigned int* __restrict__ binned,
                                                   const int* __restrict__ bucketCur,
                                                   int* __restrict__ degs,
                                                   float* __restrict__ dis,
                                                   int* __restrict__ offsets,
                                                   unsigned short* __restrict__ csr) {
    __shared__ int hist2[256 * 8];         // per (node, octant) counts -> cursors, 8 KB
    __shared__ int tsum[256];
    __shared__ uint4 scsr4[BKT_CAP / 8];   // 16 KB CSR staging
    unsigned short* scsr = (unsigned short*)scsr4;
    int b = blockIdx.x;
    int tid = threadIdx.x;
    int node0 = b << 8;
    for (int k = tid; k < 2048; k += 256) hist2[k] = 0;
    __syncthreads();
    int cnt = bucketCur[b];
    const unsigned int* bb = &binned[(size_t)b * BKT_S];
    for (int k = tid; k < cnt; k += 256) {
        unsigned int v = bb[k];
        atomicAdd(&hist2[(v & 255u) * 8 + (v >> 21)], 1);   // octant = src>>13 (0..6)
    }
    __syncthreads();
    int oc[8]; int d = 0;
#pragma unroll
    for (int o = 0; o < 8; ++o) { oc[o] = hist2[tid * 8 + o]; d += oc[o]; }
    int s = (d + 15) & ~15;          // align-16 so aggregates run full 16-edge chunks
    tsum[tid] = s;
    __syncthreads();
    for (int off = 1; off < 256; off <<= 1) {
        int t = (tid >= off) ? tsum[tid - off] : 0;
        __syncthreads();
        tsum[tid] += t;
        __syncthreads();
    }
    int excl = tsum[tid] - s;
    int tot = tsum[255];              // multiple of 16
    int csrB = b * BKT_CAP;
    int node = node0 + tid;
    if (node < N_NODES) {
        degs[node] = d;
        dis[node] = rsqrtf((float)(d + 1));
        offsets[node] = csrB + excl;
    }
    // per-node octant exclusive prefix -> in-place cursors
    int run = excl;
#pragma unroll
    for (int o = 0; o < 8; ++o) { int t = oc[o]; hist2[tid * 8 + o] = run; run += t; }
    // dummy-fill the aligned LDS region (uint2 = 4 entries; tot % 16 == 0)
    uint2 dv = make_uint2(0xC350C350u, 0xC350C350u);   // 50000 | 50000<<16
    for (int k = tid; k < (tot >> 2); k += 256) ((uint2*)scsr)[k] = dv;
    __syncthreads();
    for (int k = tid; k < cnt; k += 256) {
        unsigned int v = bb[k];
        int p = atomicAdd(&hist2[(v & 255u) * 8 + (v >> 21)], 1);
        scsr[p] = (unsigned short)(v >> 8);
    }
    __syncthreads();
    for (int k = tid; k < (tot >> 3); k += 256)
        ((uint4*)(csr + csrB))[k] = scsr4[k];
}

// ---------------------------------------------------------------------------
// K4 v3 (fused L0-aggregate + W0 GEMM + W1 GEMM), 512 threads:
//   phase A: 64 groups x 8 lanes -- ALL 64 nodes gathered in parallel (one
//            pass) into the XOR-swizzled LDS A-tile.
//   phase B: 8 waves, column-split GEMM. Wave (half=wv>>2, wq=wv&3) computes
//            rows 16*wq..16*wq+15 x cols 64*half..64*half+63 (acc[4]).
__global__ __launch_bounds__(512) void agg_gemm01(const uint4* __restrict__ xb4,
                                                  const float* __restrict__ x,
                                                  const int* __restrict__ offsets,
                                                  const int* __restrict__ degs,
                                                  const unsigned short* __restrict__ csr,
                                                  const float* __restrict__ dis,
                                                  const unsigned short* __restrict__ W0T,
                                                  const float* __restrict__ b0,
                                                  const unsigned short* __restrict__ W1T,
                                                  unsigned int* __restrict__ outb, int M) {
    __shared__ unsigned short atile[64 * 64];      // 8 KB A tile (XOR swizzled rows)
    __shared__ unsigned short tile[4][16 * 128];   // 16 KB C0 tiles (per 16-row band)
    int tid = threadIdx.x;
    int row0 = blockIdx.x * 64;
    char* at = (char*)atile;
    // ---- phase A: aggregate 64 nodes in parallel ----
    {
        int grp = tid >> 3;              // 0..63: node within tile
        int q   = tid & 7;               // uint4 col (features q*8..q*8+7)
        int i = row0 + grp;
        float a[8];
#pragma unroll
        for (int k = 0; k < 8; ++k) a[k] = 0.f;
        if (i < N_NODES) {
            int j = offsets[i];
            int e1 = j + ((degs[i] + 15) & ~15);
            for (; j < e1; j += 16) {
                int s[16];
                csr16(csr, j, s);
                uint4 r[8];
#pragma unroll
                for (int u = 0; u < 8; ++u) r[u] = xb4[(size_t)s[u] * 8 + q];
#pragma unroll
                for (int u = 0; u < 8; ++u) acc8(a, r[u]);
#pragma unroll
                for (int u = 0; u < 8; ++u) r[u] = xb4[(size_t)s[8 + u] * 8 + q];
#pragma unroll
                for (int u = 0; u < 8; ++u) acc8(a, r[u]);
            }
            float dii = dis[i];
            float d2 = dii * dii;
            float4 sx0 = ((const float4*)x)[(size_t)i * 16 + 2 * q];   // self fp32
            float4 sx1 = ((const float4*)x)[(size_t)i * 16 + 2 * q + 1];
            a[0] = dii * a[0] + d2 * sx0.x;  a[1] = dii * a[1] + d2 * sx0.y;
            a[2] = dii * a[2] + d2 * sx0.z;  a[3] = dii * a[3] + d2 * sx0.w;
            a[4] = dii * a[4] + d2 * sx1.x;  a[5] = dii * a[5] + d2 * sx1.y;
            a[6] = dii * a[6] + d2 * sx1.z;  a[7] = dii * a[7] + d2 * sx1.w;
        }
        int byte = (grp * 128 + q * 16) ^ ((grp & 7) << 4);
        *(uint4*)(at + byte) =
            make_uint4(bf16pair(a[0], a[1]), bf16pair(a[2], a[3]),
                       bf16pair(a[4], a[5]), bf16pair(a[6], a[7]));
    }
    __syncthreads();
    // ---- phase B: dual GEMM, 8 waves column-split ----
    int wv = tid >> 6;                 // 0..7
    int half = wv >> 2;                // 0..1: which 64-col half
    int wq = wv & 3;                   // 0..3: which 16-row band
    int lane = tid & 63;
    int m = lane & 15;
    int quad = lane >> 4;
    int wrow0 = row0 + wq * 16;
    char* tl = (char*)&tile[wq][0];
    f32x4 acc[4];
#pragma unroll
    for (int t = 0; t < 4; ++t) acc[t] = (f32x4){0.f, 0.f, 0.f, 0.f};
    // phase 1: K = 64 (A @ W0), A-frags from swizzled LDS A-tile
#pragma unroll
    for (int ks = 0; ks < F_IN; ks += 32) {
        int abyte = ((wq * 16 + m) * 128 + (ks + quad * 8) * 2) ^ ((m & 7) << 4);
        bf16x8 af = *(const bf16x8*)(at + abyte);
#pragma unroll
        for (int t = 0; t < 4; ++t) {
            int col = half * 64 + t * 16 + m;
            bf16x8 bf = *(const bf16x8*)&W0T[(size_t)col * F_IN + ks + quad * 8];
            acc[t] = __builtin_amdgcn_mfma_f32_16x16x32_bf16(af, bf, acc[t], 0, 0, 0);
        }
    }
    // epilogue 1: bias + relu -> bf16 -> swizzled LDS (row = quad*4+r local)
#pragma unroll
    for (int t = 0; t < 4; ++t) {
        int col = half * 64 + t * 16 + m;
        float bcol = b0[col];
#pragma unroll
        for (int r = 0; r < 4; ++r) {
            int row = quad * 4 + r;
            float v = fmaxf(acc[t][r] + bcol, 0.f);
            int byte = (row * 256 + col * 2) ^ ((row & 7) << 4);
            *(unsigned short*)(tl + byte) = bf16one(v);
        }
    }
    __syncthreads();
    // phase 2: K = 128 (C0 @ W1), A-frags from swizzled LDS
#pragma unroll
    for (int t = 0; t < 4; ++t) acc[t] = (f32x4){0.f, 0.f, 0.f, 0.f};
#pragma unroll
    for (int ks = 0; ks < F_HID; ks += 32) {
        int byte = (m * 256 + ks * 2 + quad * 16) ^ ((m & 7) << 4);
        bf16x8 af = *(const bf16x8*)(tl + byte);
#pragma unroll
        for (int t = 0; t < 4; ++t) {
            int col = half * 64 + t * 16 + m;
            bf16x8 bf = *(const bf16x8*)&W1T[(size_t)col * F_HID + ks + quad * 8];
            acc[t] = __builtin_amdgcn_mfma_f32_16x16x32_bf16(af, bf, acc[t], 0, 0, 0);
        }
    }
    // epilogue 2: dis-scale, pair-write bf16, zero pad rows
    float dr[4];
#pragma unroll
    for (int r = 0; r < 4; ++r) {
        int row = wrow0 + quad * 4 + r;
        dr[r] = (row < M) ? dis[row] : 0.f;
    }
#pragma unroll
    for (int t = 0; t < 4; ++t) {
        int col = half * 64 + t * 16 + m;
#pragma unroll
        for (int r = 0; r < 4; ++r) {
            float v = acc[t][r] * dr[r];
            float vn = __shfl_xor(v, 1, 64);    // neighbor col's value
            if ((m & 1) == 0) {
                int row = wrow0 + quad * 4 + r;
                outb[(size_t)row * 64 + (col >> 1)] = (row < M) ? bf16pair(v, vn) : 0u;
            }
        }
    }
}

// ---------------------------------------------------------------------------
// K5a v2: F=128 aggregate, group-per-node (16 groups x 16 lanes). Lane q owns
// uint4 column q end-to-end: 16 independent gathers in flight per chunk, no
// cross-lane shuffles, coalesced 256 B per row, direct uint4 store.
template <bool RELU, bool BIAS, bool SCALEOUT>
__global__ __launch_bounds__(256) void aggregate128g(const uint4* __restrict__ hb4,
                                                     const int* __restrict__ offsets,
                                                     const int* __restrict__ degs,
                                                     const unsigned short* __restrict__ csr,
                                                     const float* __restrict__ dis,
                                                     const float* __restrict__ bias,
                                                     unsigned int* __restrict__ outb) {
    int tid = threadIdx.x;
    int grp = tid >> 4;               // 0..15: node within block
    int q   = tid & 15;               // uint4 column (features q*8..q*8+7)
    int i = blockIdx.x * 16 + grp;
    if (i >= N_NODES) {
        if (i == N_NODES)             // zero dummy row for downstream gathers
            ((uint4*)outb)[(size_t)N_NODES * 16 + q] = make_uint4(0u, 0u, 0u, 0u);
        return;
    }
    float a[8];
#pragma unroll
    for (int k = 0; k < 8; ++k) a[k] = 0.f;
    int j = offsets[i];
    int e1 = j + ((degs[i] + 15) & ~15);
    for (; j < e1; j += 16) {
        int s[16];
        csr16(csr, j, s);
        uint4 r[8];
#pragma unroll
        for (int u = 0; u < 8; ++u) r[u] = hb4[(size_t)s[u] * 16 + q];
#pragma unroll
        for (int u = 0; u < 8; ++u) acc8(a, r[u]);
#pragma unroll
        for (int u = 0; u < 8; ++u) r[u] = hb4[(size_t)s[8 + u] * 16 + q];
#pragma unroll
        for (int u = 0; u < 8; ++u) acc8(a, r[u]);
    }
    uint4 su = hb4[(size_t)i * 16 + q];     // self: weight 1 in scaled domain
    acc8(a, su);
    float dii = dis[i];
#pragma unroll
    for (int k = 0; k < 8; ++k) a[k] *= dii;
    if (BIAS) {
        float4 b0 = ((const float4*)bias)[2 * q];
        float4 b1 = ((const float4*)bias)[2 * q + 1];
        a[0] += b0.x; a[1] += b0.y; a[2] += b0.z; a[3] += b0.w;
        a[4] += b1.x; a[5] += b1.y; a[6] += b1.z; a[7] += b1.w;
    }
    if (RELU) {
#pragma unroll
        for (int k = 0; k < 8; ++k) a[k] = fmaxf(a[k], 0.f);
    }
    float sc = SCALEOUT ? dii : 1.f;
    ((uint4*)outb)[(size_t)i * 16 + q] =
        make_uint4(bf16pair(sc * a[0], sc * a[1]), bf16pair(sc * a[2], sc * a[3]),
                   bf16pair(sc * a[4], sc * a[5]), bf16pair(sc * a[6], sc * a[7]));
}

// K5c: layer-2 aggregate FUSED with mean-pool, group-per-node layout.
// 256 threads = 16 groups x 16 lanes; rows staged in LDS, then pool16-style
// flush (atomics amortized over 16 nodes).
__global__ __launch_bounds__(256) void aggregate_pool(const uint4* __restrict__ hb4,
                                                      const int* __restrict__ offsets,
                                                      const int* __restrict__ degs,
                                                      const unsigned short* __restrict__ csr,
                                                      const float* __restrict__ dis,
                                                      const int* __restrict__ batch,
                                                      float* __restrict__ g_acc,
                                                      float* __restrict__ g_cnt) {
    __shared__ float pool[16][128];   // [node][k*16+q] layout (<=4-way bank conflict)
    int tid = threadIdx.x;
    int grp = tid >> 4;               // 0..15: node within block
    int q   = tid & 15;               // uint4 column (features q*8 .. q*8+7)
    int i = blockIdx.x * 16 + grp;
    float a[8];
#pragma unroll
    for (int k = 0; k < 8; ++k) a[k] = 0.f;
    if (i < N_NODES) {
        int j = offsets[i];
        int e1 = j + ((degs[i] + 15) & ~15);
        for (; j < e1; j += 16) {
            int s[16];
            csr16(csr, j, s);
            uint4 r[8];
#pragma unroll
            for (int u = 0; u < 8; ++u) r[u] = hb4[(size_t)s[u] * 16 + q];
#pragma unroll
            for (int u = 0; u < 8; ++u) acc8(a, r[u]);
#pragma unroll
            for (int u = 0; u < 8; ++u) r[u] = hb4[(size_t)s[8 + u] * 16 + q];
#pragma unroll
            for (int u = 0; u < 8; ++u) acc8(a, r[u]);
        }
        uint4 su = hb4[(size_t)i * 16 + q];   // self: weight 1 in scaled domain
        acc8(a, su);
        float dii = dis[i];
#pragma unroll
        for (int k = 0; k < 8; ++k) a[k] *= dii;
    }
#pragma unroll
    for (int k = 0; k < 8; ++k) pool[grp][k * 16 + q] = a[k];
    __syncthreads();
    // flush phase: 128 threads accumulate the 16 rows, atomics per graph change
    if (tid < 128) {
        int f = tid;                              // feature index
        int lidx = (f & 7) * 16 + (f >> 3);       // LDS index for feature f
        int base = blockIdx.x * 16;
        float acc = 0.f; int cur = -1; float cnt = 0.f;
        for (int n = 0; n < 16; ++n) {
            int i2 = base + n;
            if (i2 >= N_NODES) break;
            int b = batch[i2];
            if (b != cur) {
                if (cur >= 0) {
                    atomicAdd(&g_acc[(size_t)cur * F_HID + f], acc);
                    if (f == 0) atomicAdd(&g_cnt[cur], cnt);
                }
                cur = b; acc = 0.f; cnt = 0.f;
            }
            acc += pool[n][lidx];
            cnt += 1.f;
        }
        if (cur >= 0) {
            atomicAdd(&g_acc[(size_t)cur * F_HID + f], acc);
            if (f == 0) atomicAdd(&g_cnt[cur], cnt);
        }
    }
}

// ---------------------------------------------------------------------------
// K7: fused graph head: g2 = (g_acc/cnt)@W2 + b2; g_hid = relu(g2@Wm1+bm1);
// out = g_hid@Wm2 + bm2.  One block per graph, 512 threads.
__global__ __launch_bounds__(512) void fused_mlp(const float* __restrict__ g_acc,
                                                 const float* __restrict__ g_cnt,
                                                 const float* __restrict__ W2,
                                                 const float* __restrict__ b2,
                                                 const float* __restrict__ Wm1,
                                                 const float* __restrict__ bm1,
                                                 const float* __restrict__ Wm2,
                                                 const float* __restrict__ bm2,
                                                 float* __restrict__ out) {
    __shared__ float pool_row[F_HID];
    __shared__ float g2row[F_HID];
    __shared__ float hid[N_HID];
    int g = blockIdx.x;
    int t = threadIdx.x;              // 0..511
    if (t < F_HID) {
        float c = g_cnt[g];
        pool_row[t] = g_acc[(size_t)g * F_HID + t] / fmaxf(c, 1.0f);
    }
    __syncthreads();
    if (t < F_HID) {
        float acc = b2[t];
        for (int k = 0; k < F_HID; ++k) acc += pool_row[k] * W2[(size_t)k * F_HID + t];
        g2row[t] = acc;
    }
    __syncthreads();
    {
        float acc = bm1[t];
        for (int k = 0; k < F_HID; ++k) acc += g2row[k] * Wm1[(size_t)k * N_HID + t];
        hid[t] = fmaxf(acc, 0.f);
    }
    __syncthreads();
    if (t < N_OUT) {
        float acc = bm2[t];
        for (int k = 0; k < N_HID; ++k) acc += hid[k] * Wm2[(size_t)k * N_OUT + t];
        out[(size_t)g * N_OUT + t] = acc;
    }
}

// ---------------------------------------------------------------------------
extern "C" void kernel_launch(void* const* d_in, const int* in_sizes, int n_in,
                              void* d_out, int out_size, void* d_ws, size_t ws_size,
                              hipStream_t stream) {
    const float* x   = (const float*)d_in[0];
    const int* ei    = (const int*)d_in[1];     // [2, E] int32
    const int* batch = (const int*)d_in[2];
    const float* W0 = (const float*)d_in[3];  const float* b0 = (const float*)d_in[4];
    const float* W1 = (const float*)d_in[5];  const float* b1 = (const float*)d_in[6];
    const float* W2 = (const float*)d_in[7];  const float* b2 = (const float*)d_in[8];
    const float* Wm1 = (const float*)d_in[9];  const float* bm1 = (const float*)d_in[10];
    const float* Wm2 = (const float*)d_in[11]; const float* bm2 = (const float*)d_in[12];

    // bump allocator on d_ws, 256B-aligned slots
    char* p = (char*)d_ws;
    auto alloc = [&](size_t bytes) -> char* {
        char* r = p;
        p += (bytes + 255) & ~(size_t)255;
        return r;
    };
    // zero-init region (contiguous in allocation order)
    int*   bucketCur = (int*)alloc(NBKT * 4);
    float* g_acc  = (float*)alloc((size_t)N_GRAPHS * F_HID * 4);
    float* g_cnt  = (float*)alloc(N_GRAPHS * 4);
    size_t zero_bytes = (size_t)(p - (char*)bucketCur);
    // rest
    unsigned int* binned = (unsigned int*)alloc((size_t)NBKT * BKT_S * 4);
    int*   offsets = (int*)alloc((size_t)N_NODES * 4);
    int*   degs    = (int*)alloc((size_t)N_NODES * 4);
    float* dis     = (float*)alloc((size_t)N_NODES * 4);
    unsigned short* csr = (unsigned short*)alloc((size_t)NBKT * BKT_CAP * 2 + 32);
    unsigned int* xb     = (unsigned int*)alloc((size_t)N_PAD * F_IN / 2 * 4);   // bf16 x' (dis-scaled) + zero row
    unsigned int* h_tmpb = (unsigned int*)alloc((size_t)N_PAD * F_HID / 2 * 4);  // bf16 (dis-scaled) + zero pad
    unsigned int* h_bb   = (unsigned int*)alloc((size_t)N_PAD * F_HID / 2 * 4);  // bf16 (dis-scaled) + zero row
    unsigned short* W0Tb = (unsigned short*)alloc((size_t)128 * F_IN * 2);
    unsigned short* W1Tb = (unsigned short*)alloc((size_t)128 * F_HID * 2);
    (void)ws_size; (void)in_sizes; (void)n_in; (void)out_size;

    (void)hipMemsetAsync(bucketCur, 0, zero_bytes, stream);

    // CSR construction: privatized binning -> per-bucket deg+scatter (octant-grouped)
    bin_edges<<<NBIN_BLK, 256, 0, stream>>>(ei, bucketCur, binned);
    deg_scatter<<<NBKT, 256, 0, stream>>>(binned, bucketCur, degs, dis, offsets, csr);

    const int NCVT = N_NODES * F_IN / 4 + (F_IN + F_HID) * 128;
    cvt_all<<<(NCVT + 255) / 256, 256, 0, stream>>>(x, dis, xb, W0, W0Tb, W1, W1Tb);

    int mfma_grid = N_PAD / 64;                // 782 blocks
    int agg16_grid = N_NODES / 16 + 1;         // 3126: last block writes zero row
    int pool_grid = (N_NODES + 15) / 16;       // 3125

    // layers 0+1 front (fully fused): h_tmpb = bf16(dis * (relu((Â x')@W0+b0) @ W1))
    agg_gemm01<<<mfma_grid, 512, 0, stream>>>(
        (const uint4*)xb, x, offsets, degs, csr, dis,
        W0Tb, b0, W1Tb, h_tmpb, N_NODES);
    // layer 1 back: h_bb = bf16(dis * relu(Â h_tmp + b1))
    aggregate128g<true, true, true><<<agg16_grid, 256, 0, stream>>>(
        (const uint4*)h_tmpb, offsets, degs, csr, dis, b1, h_bb);
    // layer 2 (commuted) + pooling fused, group-per-node
    aggregate_pool<<<pool_grid, 256, 0, stream>>>(
        (const uint4*)h_bb, offsets, degs, csr, dis, batch, g_acc, g_cnt);

    // fused (W2 + MLP) head
    fused_mlp<<<N_GRAPHS, 512, 0, stream>>>(g_acc, g_cnt, W2, b2, Wm1, bm1, Wm2, bm2,
                                            (float*)d_out);
}